// Round 7
// baseline (1376.326 us; speedup 1.0000x reference)
//
#include <hip/hip_runtime.h>
#include <math.h>

typedef short short8 __attribute__((ext_vector_type(8)));
typedef short short4v __attribute__((ext_vector_type(4)));
typedef float f32x4 __attribute__((ext_vector_type(4)));

__device__ __forceinline__ unsigned short f2bf(float v){
  unsigned u = __builtin_bit_cast(unsigned, v);
  u += 0x7FFFu + ((u >> 16) & 1u);
  return (unsigned short)(u >> 16);
}
__device__ __forceinline__ float bf2f(unsigned short b){
  unsigned u = ((unsigned)b) << 16;
  return __builtin_bit_cast(float, u);
}

// ---------------------------------------------------------------------------
// degree count + all 5 weight matrices -> bf16 hi/lo transposed, one kernel.
// Segments: W11@0(4096) W12@4096(4096) W21@8192(16384) W22@24576(65536)
//           W31@90112(131072). Total 221184.
// ---------------------------------------------------------------------------
__global__ void k_deg_prep(const int* __restrict__ dstv, int* __restrict__ deg, int E,
                           const float* __restrict__ W11, const float* __restrict__ W12,
                           const float* __restrict__ W21, const float* __restrict__ W22,
                           const float* __restrict__ W31,
                           unsigned short* __restrict__ bh, unsigned short* __restrict__ bl){
  int i = blockIdx.x*blockDim.x + threadIdx.x;
  if (i < E) atomicAdd(&deg[dstv[i]], 1);
  if (i < 221184){
    const float* W; int K, kpsh, off, Nn;
    if (i < 4096)       { W=W11; K=3;   kpsh=6; off=0;     Nn=64;  }
    else if (i < 8192)  { W=W12; K=64;  kpsh=6; off=4096;  Nn=64;  }
    else if (i < 24576) { W=W21; K=64;  kpsh=6; off=8192;  Nn=256; }
    else if (i < 90112) { W=W22; K=256; kpsh=8; off=24576; Nn=256; }
    else                { W=W31; K=256; kpsh=8; off=90112; Nn=512; }
    int j = i - off;
    int Kp = 1 << kpsh;
    int n = j >> kpsh, k = j & (Kp-1);
    float v = (k < K) ? W[(size_t)k*Nn + n] : 0.0f;
    unsigned short h = f2bf(v);
    bh[i] = h;
    bl[i] = f2bf(v - bf2f(h));
  }
}

__global__ void k_scan(const int* __restrict__ deg, int* __restrict__ off,
                       int* __restrict__ cursor, int N){
  __shared__ int wpre[16];
  __shared__ int s_tot;
  __shared__ int carry;
  int tid = threadIdx.x;
  int lane = tid & 63, wv = tid >> 6;
  if (tid == 0) carry = 0;
  __syncthreads();
  for (int base = 0; base < N; base += 1024){
    int i = base + tid;
    int v = (i < N) ? deg[i] : 0;
    int incl = v;
    #pragma unroll
    for (int d = 1; d < 64; d <<= 1){
      int t = __shfl_up(incl, d, 64);
      if (lane >= d) incl += t;
    }
    if (lane == 63) wpre[wv] = incl;
    __syncthreads();
    if (tid < 16){
      int x = wpre[tid];
      int ix = x;
      #pragma unroll
      for (int d = 1; d < 16; d <<= 1){
        int t = __shfl_up(ix, d, 16);
        if (tid >= d) ix += t;
      }
      wpre[tid] = ix - x;
      if (tid == 15) s_tot = ix;
    }
    __syncthreads();
    int c = carry;
    int excl = c + wpre[wv] + (incl - v);
    if (i < N){ off[i+1] = excl + v; cursor[i] = excl; }
    __syncthreads();
    if (tid == 0) carry = c + s_tot;
    __syncthreads();
  }
  if (tid == 0) off[0] = 0;
}

__global__ void k_fill(const int* __restrict__ srcv, const int* __restrict__ dstv,
                       int* __restrict__ cursor, int* __restrict__ csr, int E){
  int e = blockIdx.x*blockDim.x + threadIdx.x;
  if (e < E){
    int d = dstv[e];
    int p = atomicAdd(&cursor[d], 1);
    csr[p] = srcv[e];
  }
}

// ---------------------------------------------------------------------------
// BN stats: 256 blocks x 256 threads; 256/HC row-streams per block.
// ---------------------------------------------------------------------------
__global__ __launch_bounds__(256)
void k_bn_stats(const unsigned short* __restrict__ x, float* __restrict__ psum,
                float* __restrict__ psq, int N, int HC){
  int f   = threadIdx.x & (HC-1);
  int sub = threadIdx.x / HC;
  int subs = 256 / HC;
  int slot = blockIdx.x*subs + sub;
  int stride = gridDim.x*subs;
  float s = 0.f, q = 0.f;
  for (int r = slot; r < N; r += stride){
    float v = bf2f(x[(size_t)r*HC + f]);
    s += v; q += v*v;
  }
  psum[(size_t)slot*HC + f] = s;
  psq [(size_t)slot*HC + f] = q;
}

__global__ void k_bn_coef(const float* __restrict__ psum, const float* __restrict__ psq,
                          const float* __restrict__ g, const float* __restrict__ b,
                          float* __restrict__ sc, float* __restrict__ sh,
                          float invN, int HC, int nb){
  int f = threadIdx.x + blockIdx.x*blockDim.x;
  if (f >= HC) return;
  float s = 0.f, q = 0.f;
  for (int r = 0; r < nb; ++r){ s += psum[(size_t)r*HC+f]; q += psq[(size_t)r*HC+f]; }
  float mu  = s*invN;
  float var = q*invN - mu*mu;
  float rs  = rsqrtf(var + 1e-5f) * g[f];
  sc[f] = rs;
  sh[f] = b[f] - mu*rs;
}

// ---------------------------------------------------------------------------
// MFMA GEMM. BM=64, BN = full width.
// AFMT 0: A fp32, 3-term hi/lo. AFMT 1: A bf16 + BN affine + lrelu(0.1),
// 3-term. AFMT 2: A bf16 exact, 2-term.
// ---------------------------------------------------------------------------
template<int BN, int AFMT>
__global__ __launch_bounds__((BN==64)?256:512)
void gemm_mfma(const void* __restrict__ Av, const unsigned short* __restrict__ Bh,
               const unsigned short* __restrict__ Bl,
               const float* __restrict__ bnsc, const float* __restrict__ bnsh,
               const float* __restrict__ a_s, const float* __restrict__ a_d,
               unsigned short* __restrict__ Pb, float* __restrict__ Ds,
               float* __restrict__ Dd, int M, int K){
  constexpr int WAVES   = (BN==64) ? 4 : 8;
  constexpr int BLOCK   = WAVES*64;
  constexpr int WAVES_N = BN/64;
  constexpr int WAVES_M = WAVES/WAVES_N;
  constexpr int WM      = 64/WAVES_M;
  constexpr int MF      = WM/16;
  constexpr int CH      = (BN==512)?64 : (BN==256)?32 : 8;
  constexpr int TERMS   = (AFMT==2) ? 2 : 3;
  const int Kp = (K + 63) & ~(int)63;

  __shared__ char lds[(TERMS==3)?16384:8192];

  int tid  = threadIdx.x;
  int lane = tid & 63;
  int wid  = tid >> 6;
  int wn = wid % WAVES_N;
  int wm = wid / WAVES_N;
  int n0w = wn*64;
  int wm0 = wm*WM;
  int m0 = blockIdx.x * 64;

  f32x4 acc[MF][4];
  #pragma unroll
  for (int i = 0; i < MF; ++i)
    #pragma unroll
    for (int j = 0; j < 4; ++j)
      acc[i][j] = (f32x4){0.f,0.f,0.f,0.f};

  constexpr int SITER = 512/BLOCK;

  for (int k0 = 0; k0 < Kp; k0 += 64){
    __syncthreads();
    #pragma unroll
    for (int it = 0; it < SITER; ++it){
      int i = it*BLOCK + tid;
      int row = i >> 3, c8 = i & 7;
      int gm = m0 + row;
      int gk = k0 + c8*8;
      int off = row*128 + ((c8 ^ (row&7))<<4);
      if constexpr (AFMT == 2){
        short8 hv = {0,0,0,0,0,0,0,0};
        if (gm < M) hv = *(const short8*)((const unsigned short*)Av + (size_t)gm*K + gk);
        *(short8*)(lds + off) = hv;
      } else if constexpr (AFMT == 1){
        short8 raw = {0,0,0,0,0,0,0,0};
        if (gm < M) raw = *(const short8*)((const unsigned short*)Av + (size_t)gm*K + gk);
        short8 hi, lo;
        #pragma unroll
        for (int j=0;j<8;++j){
          float u = bf2f((unsigned short)raw[j])*bnsc[gk+j] + bnsh[gk+j];
          u = u > 0.f ? u : 0.1f*u;
          if (gm >= M) u = 0.f;
          unsigned short hb = f2bf(u);
          hi[j] = (short)hb;
          lo[j] = (short)f2bf(u - bf2f(hb));
        }
        *(short8*)(lds + off) = hi;
        *(short8*)(lds + 8192 + off) = lo;
      } else {
        const float* A = (const float*)Av;
        float v[8];
        if (gm < M && gk + 8 <= K){
          const float* ap = A + (size_t)gm*K + gk;
          float4 x0 = *(const float4*)ap;
          float4 x1 = *(const float4*)(ap+4);
          v[0]=x0.x; v[1]=x0.y; v[2]=x0.z; v[3]=x0.w;
          v[4]=x1.x; v[5]=x1.y; v[6]=x1.z; v[7]=x1.w;
        } else {
          #pragma unroll
          for (int j=0;j<8;++j){
            int gkj = gk + j;
            v[j] = (gm < M && gkj < K) ? A[(size_t)gm*K + gkj] : 0.0f;
          }
        }
        short8 hi, lo;
        #pragma unroll
        for (int j=0;j<8;++j){
          unsigned short hb = f2bf(v[j]);
          hi[j] = (short)hb;
          lo[j] = (short)f2bf(v[j] - bf2f(hb));
        }
        *(short8*)(lds + off) = hi;
        *(short8*)(lds + 8192 + off) = lo;
      }
    }
    __syncthreads();
    #pragma unroll
    for (int kk = 0; kk < 2; ++kk){
      short8 bhf[4], blf[4];
      #pragma unroll
      for (int nf = 0; nf < 4; ++nf){
        int ncol = n0w + nf*16 + (lane & 15);
        int kidx = k0 + kk*32 + ((lane>>4)<<3);
        size_t bo = (size_t)ncol*Kp + kidx;
        bhf[nf] = *(const short8*)(Bh + bo);
        blf[nf] = *(const short8*)(Bl + bo);
      }
      #pragma unroll
      for (int mt = 0; mt < MF; ++mt){
        int row = wm0 + mt*16 + (lane & 15);
        int c8 = kk*4 + (lane>>4);
        int off = row*128 + ((c8 ^ (row&7))<<4);
        short8 ah = *(const short8*)(lds + off);
        #pragma unroll
        for (int nf = 0; nf < 4; ++nf){
          acc[mt][nf] = __builtin_amdgcn_mfma_f32_16x16x32_bf16(ah, bhf[nf], acc[mt][nf], 0,0,0);
          acc[mt][nf] = __builtin_amdgcn_mfma_f32_16x16x32_bf16(ah, blf[nf], acc[mt][nf], 0,0,0);
        }
        if constexpr (TERMS == 3){
          short8 al = *(const short8*)(lds + 8192 + off);
          #pragma unroll
          for (int nf = 0; nf < 4; ++nf)
            acc[mt][nf] = __builtin_amdgcn_mfma_f32_16x16x32_bf16(al, bhf[nf], acc[mt][nf], 0,0,0);
        }
      }
    }
  }

  float asv[4], adv[4];
  #pragma unroll
  for (int nf=0; nf<4; ++nf){
    int gcol = n0w + nf*16 + (lane&15);
    asv[nf] = a_s[gcol];
    adv[nf] = a_d[gcol];
  }
  #pragma unroll
  for (int mt = 0; mt < MF; ++mt){
    #pragma unroll
    for (int r = 0; r < 4; ++r){
      int gm = m0 + wm0 + mt*16 + ((lane>>4)<<2) + r;
      bool ok = gm < M;
      #pragma unroll
      for (int nf=0;nf<4;++nf){
        if (ok) Pb[(size_t)gm*BN + n0w + nf*16 + (lane&15)] = f2bf(acc[mt][nf][r]);
      }
      if constexpr (CH == 64){
        float ps = acc[mt][0][r]*asv[0] + acc[mt][1][r]*asv[1]
                 + acc[mt][2][r]*asv[2] + acc[mt][3][r]*asv[3];
        float pd = acc[mt][0][r]*adv[0] + acc[mt][1][r]*adv[1]
                 + acc[mt][2][r]*adv[2] + acc[mt][3][r]*adv[3];
        #pragma unroll
        for (int d2=1; d2<16; d2<<=1){ ps += __shfl_xor(ps,d2,64); pd += __shfl_xor(pd,d2,64); }
        if (ok && (lane&15)==0){
          int head = n0w >> 6;
          Ds[(size_t)gm*8 + head] = ps;
          Dd[(size_t)gm*8 + head] = pd;
        }
      } else if constexpr (CH == 32){
        float ps0 = acc[mt][0][r]*asv[0] + acc[mt][1][r]*asv[1];
        float ps1 = acc[mt][2][r]*asv[2] + acc[mt][3][r]*asv[3];
        float pd0 = acc[mt][0][r]*adv[0] + acc[mt][1][r]*adv[1];
        float pd1 = acc[mt][2][r]*adv[2] + acc[mt][3][r]*adv[3];
        #pragma unroll
        for (int d2=1; d2<16; d2<<=1){
          ps0 += __shfl_xor(ps0,d2,64); ps1 += __shfl_xor(ps1,d2,64);
          pd0 += __shfl_xor(pd0,d2,64); pd1 += __shfl_xor(pd1,d2,64);
        }
        if (ok && (lane&15)==0){
          int head = n0w >> 5;
          Ds[(size_t)gm*8 + head]     = ps0;
          Ds[(size_t)gm*8 + head + 1] = ps1;
          Dd[(size_t)gm*8 + head]     = pd0;
          Dd[(size_t)gm*8 + head + 1] = pd1;
        }
      } else {
        #pragma unroll
        for (int nf=0;nf<4;++nf){
          float ps = acc[mt][nf][r]*asv[nf];
          float pd = acc[mt][nf][r]*adv[nf];
          #pragma unroll
          for (int d2=1; d2<8; d2<<=1){ ps += __shfl_xor(ps,d2,64); pd += __shfl_xor(pd,d2,64); }
          if (ok && (lane&7)==0){
            int head = nf*2 + ((lane>>3)&1);
            Ds[(size_t)gm*8 + head] = ps;
            Dd[(size_t)gm*8 + head] = pd;
          }
        }
      }
    }
  }
}

// ---------------------------------------------------------------------------
// aggregation: bf16 h (Pb, stride HC) + fp32 dots Ds/Dd [N][8].
// Fast path (deg<64): lane-split edge parallelism — HC=64: 4 edges/iter
// (16 lanes x 4 feats each), HC=256: 2 edges/iter (32 lanes x 8 feats),
// HC=512: 1 edge/iter (64 lanes x 8 feats). Low VGPR, high occupancy.
// ---------------------------------------------------------------------------
template<int HC, int ACT>
__global__ __launch_bounds__(256)
void k_agg(const unsigned short* __restrict__ Pb, const float* __restrict__ Ds,
           const float* __restrict__ Dd, const int* __restrict__ off,
           const int* __restrict__ csr, const float* __restrict__ bias,
           unsigned short* __restrict__ outb, int N){
  __shared__ float salpha[4][512];
  int lane = threadIdx.x & 63;
  int wid  = threadIdx.x >> 6;
  int n = blockIdx.x*4 + wid;
  if (n >= N) return;
  int o0 = off[n], deg = off[n+1]-o0;

  float aldn[8];
  {
    const float* dn = Dd + (unsigned)n*8u;
    float4 x0 = *(const float4*)dn;
    float4 x1 = *(const float4*)(dn+4);
    aldn[0]=x0.x; aldn[1]=x0.y; aldn[2]=x0.z; aldn[3]=x0.w;
    aldn[4]=x1.x; aldn[5]=x1.y; aldn[6]=x1.z; aldn[7]=x1.w;
  }

  if (deg < 64){
    int nE = deg + 1;
    int myidx = (lane < deg) ? csr[o0+lane] : n;
    bool active = (lane < nE);
    float v[8];
    {
      const float* dp = Ds + (unsigned)myidx*8u;
      float4 x0 = *(const float4*)dp;
      float4 x1 = *(const float4*)(dp+4);
      float t[8] = {x0.x,x0.y,x0.z,x0.w,x1.x,x1.y,x1.z,x1.w};
      #pragma unroll
      for (int h=0;h<8;++h){
        float u = t[h] + aldn[h];
        u = u > 0.f ? u : 0.2f*u;
        v[h] = active ? u : -1e30f;
      }
    }
    float m[8];
    #pragma unroll
    for (int h=0;h<8;++h) m[h]=v[h];
    #pragma unroll
    for (int d=1; d<64; d<<=1)
      #pragma unroll
      for (int h=0;h<8;++h) m[h] = fmaxf(m[h], __shfl_xor(m[h], d, 64));
    float sv[8], s[8];
    #pragma unroll
    for (int h=0;h<8;++h){ sv[h] = active ? __expf(v[h]-m[h]) : 0.f; s[h]=sv[h]; }
    #pragma unroll
    for (int d=1; d<64; d<<=1)
      #pragma unroll
      for (int h=0;h<8;++h) s[h] += __shfl_xor(s[h], d, 64);
    if (active){
      #pragma unroll
      for (int h=0;h<8;++h) salpha[wid][lane*8+h] = sv[h] / (s[h] + 1e-16f);
    }
    asm volatile("s_waitcnt lgkmcnt(0)" ::: "memory");

    if constexpr (HC == 512){
      int myh = lane >> 3;
      float acc[8] = {0,0,0,0,0,0,0,0};
      const unsigned short* Pl = Pb + lane*8;
      for (int e=0; e<nE; ++e){
        int src = __shfl(myidx, e, 64);
        float alpha = salpha[wid][e*8 + myh];
        short8 w = *(const short8*)(Pl + (unsigned)src*512u);
        #pragma unroll
        for (int j=0;j<8;++j) acc[j] += alpha * bf2f((unsigned short)w[j]);
      }
      #pragma unroll
      for (int j=0;j<8;++j){
        int f = lane*8 + j;
        float u = acc[j] + bias[f];
        if (ACT == 1) u = fmaxf(u, 0.0f);
        outb[(unsigned)n*512u + f] = f2bf(u);
      }
    } else if constexpr (HC == 256){
      int sub = lane >> 5, fl = lane & 31;
      int h = fl >> 2;
      float acc[8] = {0,0,0,0,0,0,0,0};
      const unsigned short* Pl = Pb + fl*8;
      for (int e=0; e<nE; e+=2){
        int eg = e + sub;
        bool val = eg < nE;
        int src = __shfl(myidx, val ? eg : 0, 64);
        float alpha = val ? salpha[wid][eg*8 + h] : 0.f;
        short8 w = *(const short8*)(Pl + (unsigned)src*256u);
        #pragma unroll
        for (int j=0;j<8;++j) acc[j] += alpha * bf2f((unsigned short)w[j]);
      }
      #pragma unroll
      for (int j=0;j<8;++j) acc[j] += __shfl_xor(acc[j], 32, 64);
      if (sub == 0){
        short8 ov;
        #pragma unroll
        for (int j=0;j<8;++j){
          int f = fl*8 + j;
          float u = acc[j] + bias[f];
          if (ACT == 1) u = fmaxf(u, 0.0f);
          ov[j] = (short)f2bf(u);
        }
        *(short8*)(outb + (unsigned)n*256u + fl*8) = ov;
      }
    } else { // HC == 64
      int sub = lane >> 4, fl = lane & 15;
      int h = fl >> 1;
      float acc[4] = {0,0,0,0};
      const unsigned short* Pl = Pb + fl*4;
      for (int e=0; e<nE; e+=4){
        int eg = e + sub;
        bool val = eg < nE;
        int src = __shfl(myidx, val ? eg : 0, 64);
        float alpha = val ? salpha[wid][eg*8 + h] : 0.f;
        short4v w = *(const short4v*)(Pl + (unsigned)src*64u);
        #pragma unroll
        for (int j=0;j<4;++j) acc[j] += alpha * bf2f((unsigned short)w[j]);
      }
      #pragma unroll
      for (int j=0;j<4;++j){
        acc[j] += __shfl_xor(acc[j], 16, 64);
        acc[j] += __shfl_xor(acc[j], 32, 64);
      }
      if (sub == 0){
        short4v ov;
        #pragma unroll
        for (int j=0;j<4;++j){
          int f = fl*4 + j;
          float u = acc[j] + bias[f];
          if (ACT == 1) u = fmaxf(u, 0.0f);
          ov[j] = (short)f2bf(u);
        }
        *(short4v*)(outb + (unsigned)n*64u + fl*4) = ov;
      }
    }
  } else {
    // generic slow path (deg >= 64), R features per lane
    constexpr int R = HC/64;
    int myh = lane >> 3;
    float m[8];
    #pragma unroll
    for (int h=0;h<8;++h) m[h] = -1e30f;
    for (int e = lane; e <= deg; e += 64){
      int src = (e < deg) ? csr[o0+e] : n;
      const float* ap = Ds + (size_t)src*8;
      #pragma unroll
      for (int h=0;h<8;++h){
        float u = ap[h] + aldn[h];
        u = u > 0.f ? u : 0.2f*u;
        m[h] = fmaxf(m[h], u);
      }
    }
    #pragma unroll
    for (int d=1; d<64; d<<=1)
      #pragma unroll
      for (int h=0;h<8;++h) m[h] = fmaxf(m[h], __shfl_xor(m[h], d, 64));
    float s[8] = {0,0,0,0,0,0,0,0};
    for (int e = lane; e <= deg; e += 64){
      int src = (e < deg) ? csr[o0+e] : n;
      const float* ap = Ds + (size_t)src*8;
      #pragma unroll
      for (int h=0;h<8;++h){
        float u = ap[h] + aldn[h];
        u = u > 0.f ? u : 0.2f*u;
        s[h] += __expf(u - m[h]);
      }
    }
    #pragma unroll
    for (int d=1; d<64; d<<=1)
      #pragma unroll
      for (int h=0;h<8;++h) s[h] += __shfl_xor(s[h], d, 64);
    float mh = m[myh];
    float rsh = 1.0f/(s[myh] + 1e-16f);
    float adh = aldn[myh];
    float acc[R];
    #pragma unroll
    for (int j=0;j<R;++j) acc[j]=0.f;
    for (int e = 0; e <= deg; ++e){
      int src = (e < deg) ? csr[o0+e] : n;
      float u = Ds[(size_t)src*8 + myh] + adh;
      u = u > 0.f ? u : 0.2f*u;
      float alpha = __expf(u - mh) * rsh;
      const unsigned short* hp = Pb + (size_t)src*HC + lane*R;
      if constexpr (R == 1){
        acc[0] += alpha * bf2f(hp[0]);
      } else if constexpr (R == 4){
        short4v w = *(const short4v*)hp;
        #pragma unroll
        for (int j=0;j<4;++j) acc[j] += alpha * bf2f((unsigned short)w[j]);
      } else {
        short8 w = *(const short8*)hp;
        #pragma unroll
        for (int j=0;j<8;++j) acc[j] += alpha * bf2f((unsigned short)w[j]);
      }
    }
    #pragma unroll
    for (int j = 0; j < R; ++j){
      int f = lane*R + j;
      float u = acc[j] + bias[f];
      if (ACT == 1) u = fmaxf(u, 0.0f);
      outb[(size_t)n*HC + f] = f2bf(u);
    }
  }
}

// ---------------------------------------------------------------------------
// conv32 GEMM: bf16 A [M,512] x fp32 W [512,8] -> fp32 h8 [M,8]
// ---------------------------------------------------------------------------
__global__ __launch_bounds__(256)
void gemm8(const unsigned short* __restrict__ Qb, const float* __restrict__ W,
           float* __restrict__ h8, int M){
  int lane = threadIdx.x & 63;
  int gw = (blockIdx.x*blockDim.x + threadIdx.x) >> 6;
  int nw = (gridDim.x*blockDim.x) >> 6;
  float w[8][8];
  const float* wp = W + lane*64;
  #pragma unroll
  for (int j=0;j<8;++j){
    float4 a = *(const float4*)(wp + j*8);
    float4 b = *(const float4*)(wp + j*8 + 4);
    w[j][0]=a.x; w[j][1]=a.y; w[j][2]=a.z; w[j][3]=a.w;
    w[j][4]=b.x; w[j][5]=b.y; w[j][6]=b.z; w[j][7]=b.w;
  }
  for (int n = gw; n < M; n += nw){
    short8 v8 = *(const short8*)(Qb + (size_t)n*512 + lane*8);
    float p[8] = {0,0,0,0,0,0,0,0};
    #pragma unroll
    for (int j=0;j<8;++j){
      float x = bf2f((unsigned short)v8[j]);
      #pragma unroll
      for (int o=0;o<8;++o) p[o] += x * w[j][o];
    }
    #pragma unroll
    for (int d=1; d<64; d<<=1)
      #pragma unroll
      for (int o=0;o<8;++o) p[o] += __shfl_xor(p[o], d, 64);
    if (lane == 0){
      float4 y0 = make_float4(p[0],p[1],p[2],p[3]);
      float4 y1 = make_float4(p[4],p[5],p[6],p[7]);
      *(float4*)(h8 + (size_t)n*8)     = y0;
      *(float4*)(h8 + (size_t)n*8 + 4) = y1;
    }
  }
}

// ---------------------------------------------------------------------------
// final conv: wave-per-node
// ---------------------------------------------------------------------------
__global__ __launch_bounds__(256)
void k_final(const float* __restrict__ h8, const float* __restrict__ a_s,
             const float* __restrict__ a_d, const int* __restrict__ off,
             const int* __restrict__ csr, const float* __restrict__ b32,
             float* __restrict__ outp, int N){
  int lane = threadIdx.x & 63;
  int wv   = threadIdx.x >> 6;
  int n = blockIdx.x*4 + wv;
  if (n >= N) return;
  int o0 = off[n], deg = off[n+1]-o0;
  float asv[8], adv[8];
  #pragma unroll
  for (int h=0;h<8;++h){ asv[h]=a_s[h]; adv[h]=a_d[h]; }
  float aldn[8];
  {
    const float* hp = h8 + (size_t)n*8;
    float4 x0 = *(const float4*)hp;
    float4 x1 = *(const float4*)(hp+4);
    float hn[8] = {x0.x,x0.y,x0.z,x0.w,x1.x,x1.y,x1.z,x1.w};
    #pragma unroll
    for (int h=0;h<8;++h) aldn[h] = hn[h]*adv[h];
  }

  if (deg < 64){
    int nE = deg + 1;
    int src = (lane < deg) ? csr[o0+lane] : n;
    bool act = (lane < nE);
    float hs[8];
    {
      const float* hp = h8 + (size_t)src*8;
      float4 x0 = *(const float4*)hp;
      float4 x1 = *(const float4*)(hp+4);
      hs[0]=x0.x; hs[1]=x0.y; hs[2]=x0.z; hs[3]=x0.w;
      hs[4]=x1.x; hs[5]=x1.y; hs[6]=x1.z; hs[7]=x1.w;
    }
    float v[8];
    #pragma unroll
    for (int h=0;h<8;++h){
      float u = hs[h]*asv[h] + aldn[h];
      u = u > 0.f ? u : 0.2f*u;
      v[h] = act ? u : -1e30f;
    }
    float m[8];
    #pragma unroll
    for (int h=0;h<8;++h) m[h]=v[h];
    #pragma unroll
    for (int d=1; d<64; d<<=1)
      #pragma unroll
      for (int h=0;h<8;++h) m[h] = fmaxf(m[h], __shfl_xor(m[h], d, 64));
    float s[8], t[8];
    #pragma unroll
    for (int h=0;h<8;++h){
      float e = act ? __expf(v[h]-m[h]) : 0.f;
      s[h]=e; t[h]=e*hs[h];
    }
    #pragma unroll
    for (int d=1; d<64; d<<=1)
      #pragma unroll
      for (int h=0;h<8;++h){
        s[h] += __shfl_xor(s[h], d, 64);
        t[h] += __shfl_xor(t[h], d, 64);
      }
    if (lane == 0){
      float o = 0.f;
      #pragma unroll
      for (int h=0;h<8;++h) o += t[h]/(s[h]+1e-16f);
      o = o*0.125f + b32[0];
      outp[n] = 1.0f/(1.0f + __expf(-o));
    }
  } else if (lane == 0){
    float m[8], s[8], agg[8];
    #pragma unroll
    for (int h=0;h<8;++h){ m[h]=-1e30f; s[h]=0.f; agg[h]=0.f; }
    for (int e = 0; e <= deg; ++e){
      int src = (e < deg) ? csr[o0+e] : n;
      #pragma unroll
      for (int h=0;h<8;++h){
        float u = h8[(size_t)src*8+h]*asv[h] + aldn[h];
        u = u > 0.f ? u : 0.2f*u;
        m[h] = fmaxf(m[h], u);
      }
    }
    for (int e = 0; e <= deg; ++e){
      int src = (e < deg) ? csr[o0+e] : n;
      #pragma unroll
      for (int h=0;h<8;++h){
        float u = h8[(size_t)src*8+h]*asv[h] + aldn[h];
        u = u > 0.f ? u : 0.2f*u;
        float ex = __expf(u - m[h]);
        s[h] += ex;
        agg[h] += ex * h8[(size_t)src*8+h];
      }
    }
    float o = 0.f;
    #pragma unroll
    for (int h=0;h<8;++h) o += agg[h]/(s[h]+1e-16f);
    o = o*0.125f + b32[0];
    outp[n] = 1.0f/(1.0f + __expf(-o));
  }
}

// ---------------------------------------------------------------------------
extern "C" void kernel_launch(void* const* d_in, const int* in_sizes, int n_in,
                              void* d_out, int out_size, void* d_ws, size_t ws_size,
                              hipStream_t stream){
  int N = in_sizes[0]/3;
  int E = in_sizes[1]/2;
  const float* x    = (const float*)d_in[0];
  const int*   ei   = (const int*)  d_in[1];
  const float* W11  = (const float*)d_in[2];
  const float* as11 = (const float*)d_in[3];
  const float* ad11 = (const float*)d_in[4];
  const float* b11  = (const float*)d_in[5];
  const float* W12  = (const float*)d_in[6];
  const float* as12 = (const float*)d_in[7];
  const float* ad12 = (const float*)d_in[8];
  const float* b12  = (const float*)d_in[9];
  const float* g1   = (const float*)d_in[10];
  const float* be1  = (const float*)d_in[11];
  const float* W21  = (const float*)d_in[12];
  const float* as21 = (const float*)d_in[13];
  const float* ad21 = (const float*)d_in[14];
  const float* b21  = (const float*)d_in[15];
  const float* W22  = (const float*)d_in[16];
  const float* as22 = (const float*)d_in[17];
  const float* ad22 = (const float*)d_in[18];
  const float* b22  = (const float*)d_in[19];
  const float* g2   = (const float*)d_in[20];
  const float* be2  = (const float*)d_in[21];
  const float* W31  = (const float*)d_in[22];
  const float* as31 = (const float*)d_in[23];
  const float* ad31 = (const float*)d_in[24];
  const float* b31  = (const float*)d_in[25];
  const float* W32  = (const float*)d_in[26];
  const float* as32 = (const float*)d_in[27];
  const float* ad32 = (const float*)d_in[28];
  const float* b32  = (const float*)d_in[29];

  char* ws = (char*)d_ws;
  size_t o = 0;
  auto alloc = [&](size_t bytes)->char*{
    char* p = ws + o;
    o = (o + bytes + 255) & ~(size_t)255;
    return p;
  };
  int*   deg    = (int*)  alloc((size_t)N*4);
  int*   off    = (int*)  alloc((size_t)(N+1)*4);
  int*   cursor = (int*)  alloc((size_t)N*4);
  int*   csr    = (int*)  alloc((size_t)E*4);
  unsigned short* bh = (unsigned short*)alloc(221184*2);
  unsigned short* bl = (unsigned short*)alloc(221184*2);
  float* h8     = (float*)alloc((size_t)N*8*4);
  float* psum   = (float*)alloc(1024*64*4);   // up to 1024 slots x 64, or 256 x 256
  float* psq    = (float*)alloc(1024*64*4);
  float* bnsc   = (float*)alloc(1024);
  float* bnsh   = (float*)alloc(1024);
  unsigned short* Pb = (unsigned short*)alloc((size_t)N*512*2); // bf16 pre-agg h
  unsigned short* Qb = (unsigned short*)alloc((size_t)N*512*2); // bf16 activations
  float* Dsb    = (float*)alloc((size_t)N*8*4);
  float* Ddb    = (float*)alloc((size_t)N*8*4);
  (void)ws_size;

  const int BT11=0, BT12=4096, BT21=8192, BT22=24576, BT31=90112;

  // ---- CSR build + weight prep ----
  hipMemsetAsync(deg, 0, (size_t)N*4, stream);
  int eb = (E+255)/256;
  k_deg_prep<<<eb, 256, 0, stream>>>(ei+E, deg, E, W11, W12, W21, W22, W31, bh, bl);
  k_scan<<<1, 1024, 0, stream>>>(deg, off, cursor, N);
  k_fill<<<eb, 256, 0, stream>>>(ei, ei+E, cursor, csr, E);

  int mb = (N+63)/64;
  int nb4 = (N+3)/4;
  float invN = 1.0f/(float)N;

  // ---- conv11: 3 -> 64 (A fp32, 3-term), relu ----
  gemm_mfma<64,0><<<mb, 256, 0, stream>>>(x, bh+BT11, bl+BT11, nullptr, nullptr,
                                          as11, ad11, Pb, Dsb, Ddb, N, 3);
  k_agg<64,1><<<nb4, 256, 0, stream>>>(Pb, Dsb, Ddb, off, csr, b11, Qb, N);

  // ---- conv12: 64 -> 64 (A bf16 exact, 2-term), BN stats after ----
  gemm_mfma<64,2><<<mb, 256, 0, stream>>>(Qb, bh+BT12, bl+BT12, nullptr, nullptr,
                                          as12, ad12, Pb, Dsb, Ddb, N, 64);
  k_agg<64,0><<<nb4, 256, 0, stream>>>(Pb, Dsb, Ddb, off, csr, b12, Qb, N);
  k_bn_stats<<<256, 256, 0, stream>>>(Qb, psum, psq, N, 64);
  k_bn_coef<<<1, 64, 0, stream>>>(psum, psq, g1, be1, bnsc, bnsh, invN, 64, 1024);

  // ---- conv21: 64 -> 256 (BN+lrelu fused, 3-term), relu out ----
  gemm_mfma<256,1><<<mb, 512, 0, stream>>>(Qb, bh+BT21, bl+BT21, bnsc, bnsh,
                                           as21, ad21, Pb, Dsb, Ddb, N, 64);
  k_agg<256,1><<<nb4, 256, 0, stream>>>(Pb, Dsb, Ddb, off, csr, b21, Qb, N);

  // ---- conv22: 256 -> 256 (A bf16 exact, 2-term), BN stats ----
  gemm_mfma<256,2><<<mb, 512, 0, stream>>>(Qb, bh+BT22, bl+BT22, nullptr, nullptr,
                                           as22, ad22, Pb, Dsb, Ddb, N, 256);
  k_agg<256,0><<<nb4, 256, 0, stream>>>(Pb, Dsb, Ddb, off, csr, b22, Qb, N);
  k_bn_stats<<<256, 256, 0, stream>>>(Qb, psum, psq, N, 256);
  k_bn_coef<<<1, 256, 0, stream>>>(psum, psq, g2, be2, bnsc, bnsh, invN, 256, 256);

  // ---- conv31: 256 -> 512 (BN+lrelu fused, 3-term), relu out ----
  gemm_mfma<512,1><<<mb, 512, 0, stream>>>(Qb, bh+BT31, bl+BT31, bnsc, bnsh,
                                           as31, ad31, Pb, Dsb, Ddb, N, 256);
  k_agg<512,1><<<nb4, 256, 0, stream>>>(Pb, Dsb, Ddb, off, csr, b31, Qb, N);

  // ---- conv32: 512 -> 8x1, concat=False, mean, sigmoid ----
  gemm8<<<1024, 256, 0, stream>>>(Qb, W32, h8, N);
  k_final<<<nb4, 256, 0, stream>>>(h8, as32, ad32, off, csr, b32,
                                   (float*)d_out, N);
}

// Round 8
// 1066.796 us; speedup vs baseline: 1.2901x; 1.2901x over previous
//
#include <hip/hip_runtime.h>
#include <math.h>

typedef short short8 __attribute__((ext_vector_type(8)));
typedef short short4v __attribute__((ext_vector_type(4)));
typedef float f32x4 __attribute__((ext_vector_type(4)));

__device__ __forceinline__ unsigned short f2bf(float v){
  unsigned u = __builtin_bit_cast(unsigned, v);
  u += 0x7FFFu + ((u >> 16) & 1u);
  return (unsigned short)(u >> 16);
}
__device__ __forceinline__ float bf2f(unsigned short b){
  unsigned u = ((unsigned)b) << 16;
  return __builtin_bit_cast(float, u);
}

// ---------------------------------------------------------------------------
// degree count + all 5 weight matrices -> bf16 hi/lo transposed, one kernel.
// ---------------------------------------------------------------------------
__global__ void k_deg_prep(const int* __restrict__ dstv, int* __restrict__ deg, int E,
                           const float* __restrict__ W11, const float* __restrict__ W12,
                           const float* __restrict__ W21, const float* __restrict__ W22,
                           const float* __restrict__ W31,
                           unsigned short* __restrict__ bh, unsigned short* __restrict__ bl){
  int i = blockIdx.x*blockDim.x + threadIdx.x;
  if (i < E) atomicAdd(&deg[dstv[i]], 1);
  if (i < 221184){
    const float* W; int K, kpsh, off, Nn;
    if (i < 4096)       { W=W11; K=3;   kpsh=6; off=0;     Nn=64;  }
    else if (i < 8192)  { W=W12; K=64;  kpsh=6; off=4096;  Nn=64;  }
    else if (i < 24576) { W=W21; K=64;  kpsh=6; off=8192;  Nn=256; }
    else if (i < 90112) { W=W22; K=256; kpsh=8; off=24576; Nn=256; }
    else                { W=W31; K=256; kpsh=8; off=90112; Nn=512; }
    int j = i - off;
    int Kp = 1 << kpsh;
    int n = j >> kpsh, k = j & (Kp-1);
    float v = (k < K) ? W[(size_t)k*Nn + n] : 0.0f;
    unsigned short h = f2bf(v);
    bh[i] = h;
    bl[i] = f2bf(v - bf2f(h));
  }
}

__global__ void k_scan(const int* __restrict__ deg, int* __restrict__ off,
                       int* __restrict__ cursor, int N){
  __shared__ int wpre[16];
  __shared__ int s_tot;
  __shared__ int carry;
  int tid = threadIdx.x;
  int lane = tid & 63, wv = tid >> 6;
  if (tid == 0) carry = 0;
  __syncthreads();
  for (int base = 0; base < N; base += 1024){
    int i = base + tid;
    int v = (i < N) ? deg[i] : 0;
    int incl = v;
    #pragma unroll
    for (int d = 1; d < 64; d <<= 1){
      int t = __shfl_up(incl, d, 64);
      if (lane >= d) incl += t;
    }
    if (lane == 63) wpre[wv] = incl;
    __syncthreads();
    if (tid < 16){
      int x = wpre[tid];
      int ix = x;
      #pragma unroll
      for (int d = 1; d < 16; d <<= 1){
        int t = __shfl_up(ix, d, 16);
        if (tid >= d) ix += t;
      }
      wpre[tid] = ix - x;
      if (tid == 15) s_tot = ix;
    }
    __syncthreads();
    int c = carry;
    int excl = c + wpre[wv] + (incl - v);
    if (i < N){ off[i+1] = excl + v; cursor[i] = excl; }
    __syncthreads();
    if (tid == 0) carry = c + s_tot;
    __syncthreads();
  }
  if (tid == 0) off[0] = 0;
}

__global__ void k_fill(const int* __restrict__ srcv, const int* __restrict__ dstv,
                       int* __restrict__ cursor, int* __restrict__ csr, int E){
  int e = blockIdx.x*blockDim.x + threadIdx.x;
  if (e < E){
    int d = dstv[e];
    int p = atomicAdd(&cursor[d], 1);
    csr[p] = srcv[e];
  }
}

// ---------------------------------------------------------------------------
// BN stats: 256 blocks x 256 threads; 256/HC row-streams per block.
// ---------------------------------------------------------------------------
__global__ __launch_bounds__(256)
void k_bn_stats(const unsigned short* __restrict__ x, float* __restrict__ psum,
                float* __restrict__ psq, int N, int HC){
  int f   = threadIdx.x & (HC-1);
  int sub = threadIdx.x / HC;
  int subs = 256 / HC;
  int slot = blockIdx.x*subs + sub;
  int stride = gridDim.x*subs;
  float s = 0.f, q = 0.f;
  for (int r = slot; r < N; r += stride){
    float v = bf2f(x[(size_t)r*HC + f]);
    s += v; q += v*v;
  }
  psum[(size_t)slot*HC + f] = s;
  psq [(size_t)slot*HC + f] = q;
}

// one block per feature; 256 threads parallel-reduce the slots
__global__ __launch_bounds__(256)
void k_bn_coef(const float* __restrict__ psum, const float* __restrict__ psq,
               const float* __restrict__ g, const float* __restrict__ b,
               float* __restrict__ sc, float* __restrict__ sh,
               float invN, int HC, int nb){
  int f = blockIdx.x;
  int t = threadIdx.x;
  float s = 0.f, q = 0.f;
  for (int r = t; r < nb; r += 256){
    s += psum[(size_t)r*HC + f];
    q += psq [(size_t)r*HC + f];
  }
  #pragma unroll
  for (int d = 1; d < 64; d <<= 1){
    s += __shfl_xor(s, d, 64);
    q += __shfl_xor(q, d, 64);
  }
  __shared__ float ss[4], qq[4];
  int wv = t >> 6, ln = t & 63;
  if (ln == 0){ ss[wv] = s; qq[wv] = q; }
  __syncthreads();
  if (t == 0){
    s = ss[0]+ss[1]+ss[2]+ss[3];
    q = qq[0]+qq[1]+qq[2]+qq[3];
    float mu  = s*invN;
    float var = q*invN - mu*mu;
    float rs  = rsqrtf(var + 1e-5f) * g[f];
    sc[f] = rs;
    sh[f] = b[f] - mu*rs;
  }
}

// ---------------------------------------------------------------------------
// MFMA GEMM. BM=64, BN = full width.
// AFMT 0: A fp32, 3-term hi/lo. AFMT 1: A bf16 + BN affine + lrelu(0.1),
// 3-term. AFMT 2: A bf16 exact, 2-term.
// ---------------------------------------------------------------------------
template<int BN, int AFMT>
__global__ __launch_bounds__((BN==64)?256:512)
void gemm_mfma(const void* __restrict__ Av, const unsigned short* __restrict__ Bh,
               const unsigned short* __restrict__ Bl,
               const float* __restrict__ bnsc, const float* __restrict__ bnsh,
               const float* __restrict__ a_s, const float* __restrict__ a_d,
               unsigned short* __restrict__ Pb, float* __restrict__ Ds,
               float* __restrict__ Dd, int M, int K){
  constexpr int WAVES   = (BN==64) ? 4 : 8;
  constexpr int BLOCK   = WAVES*64;
  constexpr int WAVES_N = BN/64;
  constexpr int WAVES_M = WAVES/WAVES_N;
  constexpr int WM      = 64/WAVES_M;
  constexpr int MF      = WM/16;
  constexpr int CH      = (BN==512)?64 : (BN==256)?32 : 8;
  constexpr int TERMS   = (AFMT==2) ? 2 : 3;
  const int Kp = (K + 63) & ~(int)63;

  __shared__ char lds[(TERMS==3)?16384:8192];

  int tid  = threadIdx.x;
  int lane = tid & 63;
  int wid  = tid >> 6;
  int wn = wid % WAVES_N;
  int wm = wid / WAVES_N;
  int n0w = wn*64;
  int wm0 = wm*WM;
  int m0 = blockIdx.x * 64;

  f32x4 acc[MF][4];
  #pragma unroll
  for (int i = 0; i < MF; ++i)
    #pragma unroll
    for (int j = 0; j < 4; ++j)
      acc[i][j] = (f32x4){0.f,0.f,0.f,0.f};

  constexpr int SITER = 512/BLOCK;

  for (int k0 = 0; k0 < Kp; k0 += 64){
    __syncthreads();
    #pragma unroll
    for (int it = 0; it < SITER; ++it){
      int i = it*BLOCK + tid;
      int row = i >> 3, c8 = i & 7;
      int gm = m0 + row;
      int gk = k0 + c8*8;
      int off = row*128 + ((c8 ^ (row&7))<<4);
      if constexpr (AFMT == 2){
        short8 hv = {0,0,0,0,0,0,0,0};
        if (gm < M) hv = *(const short8*)((const unsigned short*)Av + (size_t)gm*K + gk);
        *(short8*)(lds + off) = hv;
      } else if constexpr (AFMT == 1){
        short8 raw = {0,0,0,0,0,0,0,0};
        if (gm < M) raw = *(const short8*)((const unsigned short*)Av + (size_t)gm*K + gk);
        short8 hi, lo;
        #pragma unroll
        for (int j=0;j<8;++j){
          float u = bf2f((unsigned short)raw[j])*bnsc[gk+j] + bnsh[gk+j];
          u = u > 0.f ? u : 0.1f*u;
          if (gm >= M) u = 0.f;
          unsigned short hb = f2bf(u);
          hi[j] = (short)hb;
          lo[j] = (short)f2bf(u - bf2f(hb));
        }
        *(short8*)(lds + off) = hi;
        *(short8*)(lds + 8192 + off) = lo;
      } else {
        const float* A = (const float*)Av;
        float v[8];
        if (gm < M && gk + 8 <= K){
          const float* ap = A + (size_t)gm*K + gk;
          float4 x0 = *(const float4*)ap;
          float4 x1 = *(const float4*)(ap+4);
          v[0]=x0.x; v[1]=x0.y; v[2]=x0.z; v[3]=x0.w;
          v[4]=x1.x; v[5]=x1.y; v[6]=x1.z; v[7]=x1.w;
        } else {
          #pragma unroll
          for (int j=0;j<8;++j){
            int gkj = gk + j;
            v[j] = (gm < M && gkj < K) ? A[(size_t)gm*K + gkj] : 0.0f;
          }
        }
        short8 hi, lo;
        #pragma unroll
        for (int j=0;j<8;++j){
          unsigned short hb = f2bf(v[j]);
          hi[j] = (short)hb;
          lo[j] = (short)f2bf(v[j] - bf2f(hb));
        }
        *(short8*)(lds + off) = hi;
        *(short8*)(lds + 8192 + off) = lo;
      }
    }
    __syncthreads();
    #pragma unroll
    for (int kk = 0; kk < 2; ++kk){
      short8 bhf[4], blf[4];
      #pragma unroll
      for (int nf = 0; nf < 4; ++nf){
        int ncol = n0w + nf*16 + (lane & 15);
        int kidx = k0 + kk*32 + ((lane>>4)<<3);
        size_t bo = (size_t)ncol*Kp + kidx;
        bhf[nf] = *(const short8*)(Bh + bo);
        blf[nf] = *(const short8*)(Bl + bo);
      }
      #pragma unroll
      for (int mt = 0; mt < MF; ++mt){
        int row = wm0 + mt*16 + (lane & 15);
        int c8 = kk*4 + (lane>>4);
        int off = row*128 + ((c8 ^ (row&7))<<4);
        short8 ah = *(const short8*)(lds + off);
        #pragma unroll
        for (int nf = 0; nf < 4; ++nf){
          acc[mt][nf] = __builtin_amdgcn_mfma_f32_16x16x32_bf16(ah, bhf[nf], acc[mt][nf], 0,0,0);
          acc[mt][nf] = __builtin_amdgcn_mfma_f32_16x16x32_bf16(ah, blf[nf], acc[mt][nf], 0,0,0);
        }
        if constexpr (TERMS == 3){
          short8 al = *(const short8*)(lds + 8192 + off);
          #pragma unroll
          for (int nf = 0; nf < 4; ++nf)
            acc[mt][nf] = __builtin_amdgcn_mfma_f32_16x16x32_bf16(al, bhf[nf], acc[mt][nf], 0,0,0);
        }
      }
    }
  }

  float asv[4], adv[4];
  #pragma unroll
  for (int nf=0; nf<4; ++nf){
    int gcol = n0w + nf*16 + (lane&15);
    asv[nf] = a_s[gcol];
    adv[nf] = a_d[gcol];
  }
  #pragma unroll
  for (int mt = 0; mt < MF; ++mt){
    #pragma unroll
    for (int r = 0; r < 4; ++r){
      int gm = m0 + wm0 + mt*16 + ((lane>>4)<<2) + r;
      bool ok = gm < M;
      #pragma unroll
      for (int nf=0;nf<4;++nf){
        if (ok) Pb[(size_t)gm*BN + n0w + nf*16 + (lane&15)] = f2bf(acc[mt][nf][r]);
      }
      if constexpr (CH == 64){
        float ps = acc[mt][0][r]*asv[0] + acc[mt][1][r]*asv[1]
                 + acc[mt][2][r]*asv[2] + acc[mt][3][r]*asv[3];
        float pd = acc[mt][0][r]*adv[0] + acc[mt][1][r]*adv[1]
                 + acc[mt][2][r]*adv[2] + acc[mt][3][r]*adv[3];
        #pragma unroll
        for (int d2=1; d2<16; d2<<=1){ ps += __shfl_xor(ps,d2,64); pd += __shfl_xor(pd,d2,64); }
        if (ok && (lane&15)==0){
          int head = n0w >> 6;
          Ds[(size_t)gm*8 + head] = ps;
          Dd[(size_t)gm*8 + head] = pd;
        }
      } else if constexpr (CH == 32){
        float ps0 = acc[mt][0][r]*asv[0] + acc[mt][1][r]*asv[1];
        float ps1 = acc[mt][2][r]*asv[2] + acc[mt][3][r]*asv[3];
        float pd0 = acc[mt][0][r]*adv[0] + acc[mt][1][r]*adv[1];
        float pd1 = acc[mt][2][r]*adv[2] + acc[mt][3][r]*adv[3];
        #pragma unroll
        for (int d2=1; d2<16; d2<<=1){
          ps0 += __shfl_xor(ps0,d2,64); ps1 += __shfl_xor(ps1,d2,64);
          pd0 += __shfl_xor(pd0,d2,64); pd1 += __shfl_xor(pd1,d2,64);
        }
        if (ok && (lane&15)==0){
          int head = n0w >> 5;
          Ds[(size_t)gm*8 + head]     = ps0;
          Ds[(size_t)gm*8 + head + 1] = ps1;
          Dd[(size_t)gm*8 + head]     = pd0;
          Dd[(size_t)gm*8 + head + 1] = pd1;
        }
      } else {
        #pragma unroll
        for (int nf=0;nf<4;++nf){
          float ps = acc[mt][nf][r]*asv[nf];
          float pd = acc[mt][nf][r]*adv[nf];
          #pragma unroll
          for (int d2=1; d2<8; d2<<=1){ ps += __shfl_xor(ps,d2,64); pd += __shfl_xor(pd,d2,64); }
          if (ok && (lane&7)==0){
            int head = nf*2 + ((lane>>3)&1);
            Ds[(size_t)gm*8 + head] = ps;
            Dd[(size_t)gm*8 + head] = pd;
          }
        }
      }
    }
  }
}

// ---------------------------------------------------------------------------
// aggregation: bf16 h (Pb, stride HC) + fp32 dots Ds/Dd [N][8].
// Fast path (deg<64): lane-split edge parallelism.
// ---------------------------------------------------------------------------
template<int HC, int ACT>
__global__ __launch_bounds__(256)
void k_agg(const unsigned short* __restrict__ Pb, const float* __restrict__ Ds,
           const float* __restrict__ Dd, const int* __restrict__ off,
           const int* __restrict__ csr, const float* __restrict__ bias,
           unsigned short* __restrict__ outb, int N){
  __shared__ float salpha[4][512];
  int lane = threadIdx.x & 63;
  int wid  = threadIdx.x >> 6;
  int n = blockIdx.x*4 + wid;
  if (n >= N) return;
  int o0 = off[n], deg = off[n+1]-o0;

  float aldn[8];
  {
    const float* dn = Dd + (unsigned)n*8u;
    float4 x0 = *(const float4*)dn;
    float4 x1 = *(const float4*)(dn+4);
    aldn[0]=x0.x; aldn[1]=x0.y; aldn[2]=x0.z; aldn[3]=x0.w;
    aldn[4]=x1.x; aldn[5]=x1.y; aldn[6]=x1.z; aldn[7]=x1.w;
  }

  if (deg < 64){
    int nE = deg + 1;
    int myidx = (lane < deg) ? csr[o0+lane] : n;
    bool active = (lane < nE);
    float v[8];
    {
      const float* dp = Ds + (unsigned)myidx*8u;
      float4 x0 = *(const float4*)dp;
      float4 x1 = *(const float4*)(dp+4);
      float t[8] = {x0.x,x0.y,x0.z,x0.w,x1.x,x1.y,x1.z,x1.w};
      #pragma unroll
      for (int h=0;h<8;++h){
        float u = t[h] + aldn[h];
        u = u > 0.f ? u : 0.2f*u;
        v[h] = active ? u : -1e30f;
      }
    }
    float m[8];
    #pragma unroll
    for (int h=0;h<8;++h) m[h]=v[h];
    #pragma unroll
    for (int d=1; d<64; d<<=1)
      #pragma unroll
      for (int h=0;h<8;++h) m[h] = fmaxf(m[h], __shfl_xor(m[h], d, 64));
    float sv[8], s[8];
    #pragma unroll
    for (int h=0;h<8;++h){ sv[h] = active ? __expf(v[h]-m[h]) : 0.f; s[h]=sv[h]; }
    #pragma unroll
    for (int d=1; d<64; d<<=1)
      #pragma unroll
      for (int h=0;h<8;++h) s[h] += __shfl_xor(s[h], d, 64);
    if (active){
      #pragma unroll
      for (int h=0;h<8;++h) salpha[wid][lane*8+h] = sv[h] / (s[h] + 1e-16f);
    }
    asm volatile("s_waitcnt lgkmcnt(0)" ::: "memory");

    if constexpr (HC == 512){
      int myh = lane >> 3;
      float acc[8] = {0,0,0,0,0,0,0,0};
      const unsigned short* Pl = Pb + lane*8;
      for (int e=0; e<nE; ++e){
        int src = __shfl(myidx, e, 64);
        float alpha = salpha[wid][e*8 + myh];
        short8 w = *(const short8*)(Pl + (unsigned)src*512u);
        #pragma unroll
        for (int j=0;j<8;++j) acc[j] += alpha * bf2f((unsigned short)w[j]);
      }
      #pragma unroll
      for (int j=0;j<8;++j){
        int f = lane*8 + j;
        float u = acc[j] + bias[f];
        if (ACT == 1) u = fmaxf(u, 0.0f);
        outb[(unsigned)n*512u + f] = f2bf(u);
      }
    } else if constexpr (HC == 256){
      int sub = lane >> 5, fl = lane & 31;
      int h = fl >> 2;
      float acc[8] = {0,0,0,0,0,0,0,0};
      const unsigned short* Pl = Pb + fl*8;
      for (int e=0; e<nE; e+=2){
        int eg = e + sub;
        bool val = eg < nE;
        int src = __shfl(myidx, val ? eg : 0, 64);
        float alpha = val ? salpha[wid][eg*8 + h] : 0.f;
        short8 w = *(const short8*)(Pl + (unsigned)src*256u);
        #pragma unroll
        for (int j=0;j<8;++j) acc[j] += alpha * bf2f((unsigned short)w[j]);
      }
      #pragma unroll
      for (int j=0;j<8;++j) acc[j] += __shfl_xor(acc[j], 32, 64);
      if (sub == 0){
        short8 ov;
        #pragma unroll
        for (int j=0;j<8;++j){
          int f = fl*8 + j;
          float u = acc[j] + bias[f];
          if (ACT == 1) u = fmaxf(u, 0.0f);
          ov[j] = (short)f2bf(u);
        }
        *(short8*)(outb + (unsigned)n*256u + fl*8) = ov;
      }
    } else { // HC == 64
      int sub = lane >> 4, fl = lane & 15;
      int h = fl >> 1;
      float acc[4] = {0,0,0,0};
      const unsigned short* Pl = Pb + fl*4;
      for (int e=0; e<nE; e+=4){
        int eg = e + sub;
        bool val = eg < nE;
        int src = __shfl(myidx, val ? eg : 0, 64);
        float alpha = val ? salpha[wid][eg*8 + h] : 0.f;
        short4v w = *(const short4v*)(Pl + (unsigned)src*64u);
        #pragma unroll
        for (int j=0;j<4;++j) acc[j] += alpha * bf2f((unsigned short)w[j]);
      }
      #pragma unroll
      for (int j=0;j<4;++j){
        acc[j] += __shfl_xor(acc[j], 16, 64);
        acc[j] += __shfl_xor(acc[j], 32, 64);
      }
      if (sub == 0){
        short4v ov;
        #pragma unroll
        for (int j=0;j<4;++j){
          int f = fl*4 + j;
          float u = acc[j] + bias[f];
          if (ACT == 1) u = fmaxf(u, 0.0f);
          ov[j] = (short)f2bf(u);
        }
        *(short4v*)(outb + (unsigned)n*64u + fl*4) = ov;
      }
    }
  } else {
    constexpr int R = HC/64;
    int myh = lane >> 3;
    float m[8];
    #pragma unroll
    for (int h=0;h<8;++h) m[h] = -1e30f;
    for (int e = lane; e <= deg; e += 64){
      int src = (e < deg) ? csr[o0+e] : n;
      const float* ap = Ds + (size_t)src*8;
      #pragma unroll
      for (int h=0;h<8;++h){
        float u = ap[h] + aldn[h];
        u = u > 0.f ? u : 0.2f*u;
        m[h] = fmaxf(m[h], u);
      }
    }
    #pragma unroll
    for (int d=1; d<64; d<<=1)
      #pragma unroll
      for (int h=0;h<8;++h) m[h] = fmaxf(m[h], __shfl_xor(m[h], d, 64));
    float s[8] = {0,0,0,0,0,0,0,0};
    for (int e = lane; e <= deg; e += 64){
      int src = (e < deg) ? csr[o0+e] : n;
      const float* ap = Ds + (size_t)src*8;
      #pragma unroll
      for (int h=0;h<8;++h){
        float u = ap[h] + aldn[h];
        u = u > 0.f ? u : 0.2f*u;
        s[h] += __expf(u - m[h]);
      }
    }
    #pragma unroll
    for (int d=1; d<64; d<<=1)
      #pragma unroll
      for (int h=0;h<8;++h) s[h] += __shfl_xor(s[h], d, 64);
    float mh = m[myh];
    float rsh = 1.0f/(s[myh] + 1e-16f);
    float adh = aldn[myh];
    float acc[R];
    #pragma unroll
    for (int j=0;j<R;++j) acc[j]=0.f;
    for (int e = 0; e <= deg; ++e){
      int src = (e < deg) ? csr[o0+e] : n;
      float u = Ds[(size_t)src*8 + myh] + adh;
      u = u > 0.f ? u : 0.2f*u;
      float alpha = __expf(u - mh) * rsh;
      const unsigned short* hp = Pb + (size_t)src*HC + lane*R;
      if constexpr (R == 1){
        acc[0] += alpha * bf2f(hp[0]);
      } else if constexpr (R == 4){
        short4v w = *(const short4v*)hp;
        #pragma unroll
        for (int j=0;j<4;++j) acc[j] += alpha * bf2f((unsigned short)w[j]);
      } else {
        short8 w = *(const short8*)hp;
        #pragma unroll
        for (int j=0;j<8;++j) acc[j] += alpha * bf2f((unsigned short)w[j]);
      }
    }
    #pragma unroll
    for (int j = 0; j < R; ++j){
      int f = lane*R + j;
      float u = acc[j] + bias[f];
      if (ACT == 1) u = fmaxf(u, 0.0f);
      outb[(size_t)n*HC + f] = f2bf(u);
    }
  }
}

// ---------------------------------------------------------------------------
// conv32 GEMM: bf16 A [M,512] x fp32 W [512,8] -> fp32 h8 [M,8]
// ---------------------------------------------------------------------------
__global__ __launch_bounds__(256)
void gemm8(const unsigned short* __restrict__ Qb, const float* __restrict__ W,
           float* __restrict__ h8, int M){
  int lane = threadIdx.x & 63;
  int gw = (blockIdx.x*blockDim.x + threadIdx.x) >> 6;
  int nw = (gridDim.x*blockDim.x) >> 6;
  float w[8][8];
  const float* wp = W + lane*64;
  #pragma unroll
  for (int j=0;j<8;++j){
    float4 a = *(const float4*)(wp + j*8);
    float4 b = *(const float4*)(wp + j*8 + 4);
    w[j][0]=a.x; w[j][1]=a.y; w[j][2]=a.z; w[j][3]=a.w;
    w[j][4]=b.x; w[j][5]=b.y; w[j][6]=b.z; w[j][7]=b.w;
  }
  for (int n = gw; n < M; n += nw){
    short8 v8 = *(const short8*)(Qb + (size_t)n*512 + lane*8);
    float p[8] = {0,0,0,0,0,0,0,0};
    #pragma unroll
    for (int j=0;j<8;++j){
      float x = bf2f((unsigned short)v8[j]);
      #pragma unroll
      for (int o=0;o<8;++o) p[o] += x * w[j][o];
    }
    #pragma unroll
    for (int d=1; d<64; d<<=1)
      #pragma unroll
      for (int o=0;o<8;++o) p[o] += __shfl_xor(p[o], d, 64);
    if (lane == 0){
      float4 y0 = make_float4(p[0],p[1],p[2],p[3]);
      float4 y1 = make_float4(p[4],p[5],p[6],p[7]);
      *(float4*)(h8 + (size_t)n*8)     = y0;
      *(float4*)(h8 + (size_t)n*8 + 4) = y1;
    }
  }
}

// ---------------------------------------------------------------------------
// final conv: wave-per-node
// ---------------------------------------------------------------------------
__global__ __launch_bounds__(256)
void k_final(const float* __restrict__ h8, const float* __restrict__ a_s,
             const float* __restrict__ a_d, const int* __restrict__ off,
             const int* __restrict__ csr, const float* __restrict__ b32,
             float* __restrict__ outp, int N){
  int lane = threadIdx.x & 63;
  int wv   = threadIdx.x >> 6;
  int n = blockIdx.x*4 + wv;
  if (n >= N) return;
  int o0 = off[n], deg = off[n+1]-o0;
  float asv[8], adv[8];
  #pragma unroll
  for (int h=0;h<8;++h){ asv[h]=a_s[h]; adv[h]=a_d[h]; }
  float aldn[8];
  {
    const float* hp = h8 + (size_t)n*8;
    float4 x0 = *(const float4*)hp;
    float4 x1 = *(const float4*)(hp+4);
    float hn[8] = {x0.x,x0.y,x0.z,x0.w,x1.x,x1.y,x1.z,x1.w};
    #pragma unroll
    for (int h=0;h<8;++h) aldn[h] = hn[h]*adv[h];
  }

  if (deg < 64){
    int nE = deg + 1;
    int src = (lane < deg) ? csr[o0+lane] : n;
    bool act = (lane < nE);
    float hs[8];
    {
      const float* hp = h8 + (size_t)src*8;
      float4 x0 = *(const float4*)hp;
      float4 x1 = *(const float4*)(hp+4);
      hs[0]=x0.x; hs[1]=x0.y; hs[2]=x0.z; hs[3]=x0.w;
      hs[4]=x1.x; hs[5]=x1.y; hs[6]=x1.z; hs[7]=x1.w;
    }
    float v[8];
    #pragma unroll
    for (int h=0;h<8;++h){
      float u = hs[h]*asv[h] + aldn[h];
      u = u > 0.f ? u : 0.2f*u;
      v[h] = act ? u : -1e30f;
    }
    float m[8];
    #pragma unroll
    for (int h=0;h<8;++h) m[h]=v[h];
    #pragma unroll
    for (int d=1; d<64; d<<=1)
      #pragma unroll
      for (int h=0;h<8;++h) m[h] = fmaxf(m[h], __shfl_xor(m[h], d, 64));
    float s[8], t[8];
    #pragma unroll
    for (int h=0;h<8;++h){
      float e = act ? __expf(v[h]-m[h]) : 0.f;
      s[h]=e; t[h]=e*hs[h];
    }
    #pragma unroll
    for (int d=1; d<64; d<<=1)
      #pragma unroll
      for (int h=0;h<8;++h){
        s[h] += __shfl_xor(s[h], d, 64);
        t[h] += __shfl_xor(t[h], d, 64);
      }
    if (lane == 0){
      float o = 0.f;
      #pragma unroll
      for (int h=0;h<8;++h) o += t[h]/(s[h]+1e-16f);
      o = o*0.125f + b32[0];
      outp[n] = 1.0f/(1.0f + __expf(-o));
    }
  } else if (lane == 0){
    float m[8], s[8], agg[8];
    #pragma unroll
    for (int h=0;h<8;++h){ m[h]=-1e30f; s[h]=0.f; agg[h]=0.f; }
    for (int e = 0; e <= deg; ++e){
      int src = (e < deg) ? csr[o0+e] : n;
      #pragma unroll
      for (int h=0;h<8;++h){
        float u = h8[(size_t)src*8+h]*asv[h] + aldn[h];
        u = u > 0.f ? u : 0.2f*u;
        m[h] = fmaxf(m[h], u);
      }
    }
    for (int e = 0; e <= deg; ++e){
      int src = (e < deg) ? csr[o0+e] : n;
      #pragma unroll
      for (int h=0;h<8;++h){
        float u = h8[(size_t)src*8+h]*asv[h] + aldn[h];
        u = u > 0.f ? u : 0.2f*u;
        float ex = __expf(u - m[h]);
        s[h] += ex;
        agg[h] += ex * h8[(size_t)src*8+h];
      }
    }
    float o = 0.f;
    #pragma unroll
    for (int h=0;h<8;++h) o += agg[h]/(s[h]+1e-16f);
    o = o*0.125f + b32[0];
    outp[n] = 1.0f/(1.0f + __expf(-o));
  }
}

// ---------------------------------------------------------------------------
extern "C" void kernel_launch(void* const* d_in, const int* in_sizes, int n_in,
                              void* d_out, int out_size, void* d_ws, size_t ws_size,
                              hipStream_t stream){
  int N = in_sizes[0]/3;
  int E = in_sizes[1]/2;
  const float* x    = (const float*)d_in[0];
  const int*   ei   = (const int*)  d_in[1];
  const float* W11  = (const float*)d_in[2];
  const float* as11 = (const float*)d_in[3];
  const float* ad11 = (const float*)d_in[4];
  const float* b11  = (const float*)d_in[5];
  const float* W12  = (const float*)d_in[6];
  const float* as12 = (const float*)d_in[7];
  const float* ad12 = (const float*)d_in[8];
  const float* b12  = (const float*)d_in[9];
  const float* g1   = (const float*)d_in[10];
  const float* be1  = (const float*)d_in[11];
  const float* W21  = (const float*)d_in[12];
  const float* as21 = (const float*)d_in[13];
  const float* ad21 = (const float*)d_in[14];
  const float* b21  = (const float*)d_in[15];
  const float* W22  = (const float*)d_in[16];
  const float* as22 = (const float*)d_in[17];
  const float* ad22 = (const float*)d_in[18];
  const float* b22  = (const float*)d_in[19];
  const float* g2   = (const float*)d_in[20];
  const float* be2  = (const float*)d_in[21];
  const float* W31  = (const float*)d_in[22];
  const float* as31 = (const float*)d_in[23];
  const float* ad31 = (const float*)d_in[24];
  const float* b31  = (const float*)d_in[25];
  const float* W32  = (const float*)d_in[26];
  const float* as32 = (const float*)d_in[27];
  const float* ad32 = (const float*)d_in[28];
  const float* b32  = (const float*)d_in[29];

  char* ws = (char*)d_ws;
  size_t o = 0;
  auto alloc = [&](size_t bytes)->char*{
    char* p = ws + o;
    o = (o + bytes + 255) & ~(size_t)255;
    return p;
  };
  int*   deg    = (int*)  alloc((size_t)N*4);
  int*   off    = (int*)  alloc((size_t)(N+1)*4);
  int*   cursor = (int*)  alloc((size_t)N*4);
  int*   csr    = (int*)  alloc((size_t)E*4);
  unsigned short* bh = (unsigned short*)alloc(221184*2);
  unsigned short* bl = (unsigned short*)alloc(221184*2);
  float* h8     = (float*)alloc((size_t)N*8*4);
  float* psum   = (float*)alloc(1024*64*4);
  float* psq    = (float*)alloc(1024*64*4);
  float* bnsc   = (float*)alloc(1024);
  float* bnsh   = (float*)alloc(1024);
  unsigned short* Pb = (unsigned short*)alloc((size_t)N*512*2);
  unsigned short* Qb = (unsigned short*)alloc((size_t)N*512*2);
  float* Dsb    = (float*)alloc((size_t)N*8*4);
  float* Ddb    = (float*)alloc((size_t)N*8*4);
  (void)ws_size;

  const int BT11=0, BT12=4096, BT21=8192, BT22=24576, BT31=90112;

  // ---- CSR build + weight prep ----
  hipMemsetAsync(deg, 0, (size_t)N*4, stream);
  int eb = (E+255)/256;
  k_deg_prep<<<eb, 256, 0, stream>>>(ei+E, deg, E, W11, W12, W21, W22, W31, bh, bl);
  k_scan<<<1, 1024, 0, stream>>>(deg, off, cursor, N);
  k_fill<<<eb, 256, 0, stream>>>(ei, ei+E, cursor, csr, E);

  int mb = (N+63)/64;
  int nb4 = (N+3)/4;
  float invN = 1.0f/(float)N;

  // ---- conv11: 3 -> 64 (A fp32, 3-term), relu ----
  gemm_mfma<64,0><<<mb, 256, 0, stream>>>(x, bh+BT11, bl+BT11, nullptr, nullptr,
                                          as11, ad11, Pb, Dsb, Ddb, N, 3);
  k_agg<64,1><<<nb4, 256, 0, stream>>>(Pb, Dsb, Ddb, off, csr, b11, Qb, N);

  // ---- conv12: 64 -> 64 (A bf16 exact, 2-term), BN stats after ----
  gemm_mfma<64,2><<<mb, 256, 0, stream>>>(Qb, bh+BT12, bl+BT12, nullptr, nullptr,
                                          as12, ad12, Pb, Dsb, Ddb, N, 64);
  k_agg<64,0><<<nb4, 256, 0, stream>>>(Pb, Dsb, Ddb, off, csr, b12, Qb, N);
  k_bn_stats<<<256, 256, 0, stream>>>(Qb, psum, psq, N, 64);
  k_bn_coef<<<64, 256, 0, stream>>>(psum, psq, g1, be1, bnsc, bnsh, invN, 64, 1024);

  // ---- conv21: 64 -> 256 (BN+lrelu fused, 3-term), relu out ----
  gemm_mfma<256,1><<<mb, 512, 0, stream>>>(Qb, bh+BT21, bl+BT21, bnsc, bnsh,
                                           as21, ad21, Pb, Dsb, Ddb, N, 64);
  k_agg<256,1><<<nb4, 256, 0, stream>>>(Pb, Dsb, Ddb, off, csr, b21, Qb, N);

  // ---- conv22: 256 -> 256 (A bf16 exact, 2-term), BN stats ----
  gemm_mfma<256,2><<<mb, 512, 0, stream>>>(Qb, bh+BT22, bl+BT22, nullptr, nullptr,
                                           as22, ad22, Pb, Dsb, Ddb, N, 256);
  k_agg<256,0><<<nb4, 256, 0, stream>>>(Pb, Dsb, Ddb, off, csr, b22, Qb, N);
  k_bn_stats<<<256, 256, 0, stream>>>(Qb, psum, psq, N, 256);
  k_bn_coef<<<256, 256, 0, stream>>>(psum, psq, g2, be2, bnsc, bnsh, invN, 256, 256);

  // ---- conv31: 256 -> 512 (BN+lrelu fused, 3-term), relu out ----
  gemm_mfma<512,1><<<mb, 512, 0, stream>>>(Qb, bh+BT31, bl+BT31, bnsc, bnsh,
                                           as31, ad31, Pb, Dsb, Ddb, N, 256);
  k_agg<512,1><<<nb4, 256, 0, stream>>>(Pb, Dsb, Ddb, off, csr, b31, Qb, N);

  // ---- conv32: 512 -> 8x1, concat=False, mean, sigmoid ----
  gemm8<<<1024, 256, 0, stream>>>(Qb, W32, h8, N);
  k_final<<<nb4, 256, 0, stream>>>(h8, as32, ad32, off, csr, b32,
                                   (float*)d_out, N);
}

// Round 9
// 1025.410 us; speedup vs baseline: 1.3422x; 1.0404x over previous
//
#include <hip/hip_runtime.h>
#include <math.h>

typedef short short8 __attribute__((ext_vector_type(8)));
typedef short short4v __attribute__((ext_vector_type(4)));
typedef float f32x4 __attribute__((ext_vector_type(4)));

__device__ __forceinline__ unsigned short f2bf(float v){
  unsigned u = __builtin_bit_cast(unsigned, v);
  u += 0x7FFFu + ((u >> 16) & 1u);
  return (unsigned short)(u >> 16);
}
__device__ __forceinline__ float bf2f(unsigned short b){
  unsigned u = ((unsigned)b) << 16;
  return __builtin_bit_cast(float, u);
}

// ---------------------------------------------------------------------------
// degree count + all 5 weight matrices -> bf16 hi/lo transposed, one kernel.
// ---------------------------------------------------------------------------
__global__ void k_deg_prep(const int* __restrict__ dstv, int* __restrict__ deg, int E,
                           const float* __restrict__ W11, const float* __restrict__ W12,
                           const float* __restrict__ W21, const float* __restrict__ W22,
                           const float* __restrict__ W31,
                           unsigned short* __restrict__ bh, unsigned short* __restrict__ bl){
  int i = blockIdx.x*blockDim.x + threadIdx.x;
  if (i < E) atomicAdd(&deg[dstv[i]], 1);
  if (i < 221184){
    const float* W; int K, kpsh, off, Nn;
    if (i < 4096)       { W=W11; K=3;   kpsh=6; off=0;     Nn=64;  }
    else if (i < 8192)  { W=W12; K=64;  kpsh=6; off=4096;  Nn=64;  }
    else if (i < 24576) { W=W21; K=64;  kpsh=6; off=8192;  Nn=256; }
    else if (i < 90112) { W=W22; K=256; kpsh=8; off=24576; Nn=256; }
    else                { W=W31; K=256; kpsh=8; off=90112; Nn=512; }
    int j = i - off;
    int Kp = 1 << kpsh;
    int n = j >> kpsh, k = j & (Kp-1);
    float v = (k < K) ? W[(size_t)k*Nn + n] : 0.0f;
    unsigned short h = f2bf(v);
    bh[i] = h;
    bl[i] = f2bf(v - bf2f(h));
  }
}

// ---------------------------------------------------------------------------
// decoupled 3-phase exclusive scan of deg[N]
// ---------------------------------------------------------------------------
__global__ __launch_bounds__(1024)
void k_scan1(const int* __restrict__ deg, int* __restrict__ off,
             int* __restrict__ bsum, int N){
  __shared__ int wpre[16];
  int tid = threadIdx.x;
  int lane = tid & 63, wv = tid >> 6;
  int i = blockIdx.x*1024 + tid;
  int v = (i < N) ? deg[i] : 0;
  int incl = v;
  #pragma unroll
  for (int d = 1; d < 64; d <<= 1){
    int t = __shfl_up(incl, d, 64);
    if (lane >= d) incl += t;
  }
  if (lane == 63) wpre[wv] = incl;
  __syncthreads();
  if (tid < 16){
    int x = wpre[tid];
    int ix = x;
    #pragma unroll
    for (int d = 1; d < 16; d <<= 1){
      int t = __shfl_up(ix, d, 16);
      if (tid >= d) ix += t;
    }
    wpre[tid] = ix - x;
    if (tid == 15) bsum[blockIdx.x] = ix;
  }
  __syncthreads();
  if (i < N) off[i+1] = wpre[wv] + incl;   // inclusive within block
}

__global__ void k_scan2(int* __restrict__ bsum, int* __restrict__ bpre, int nb){
  int t = threadIdx.x;   // 64 threads, nb <= 64
  int v = (t < nb) ? bsum[t] : 0;
  int incl = v;
  #pragma unroll
  for (int d = 1; d < 64; d <<= 1){
    int u = __shfl_up(incl, d, 64);
    if (t >= d) incl += u;
  }
  if (t < nb) bpre[t] = incl - v;  // exclusive prefix of block sums
}

__global__ __launch_bounds__(1024)
void k_scan3(const int* __restrict__ deg, int* __restrict__ off,
             const int* __restrict__ bpre, int* __restrict__ cursor, int N){
  int i = blockIdx.x*1024 + threadIdx.x;
  if (i < N){
    int base = bpre[blockIdx.x];
    int incl = off[i+1] + base;
    off[i+1] = incl;
    cursor[i] = incl - deg[i];
    if (i == 0) off[0] = 0;
  }
}

__global__ void k_fill(const int* __restrict__ srcv, const int* __restrict__ dstv,
                       int* __restrict__ cursor, int* __restrict__ csr, int E){
  int e = blockIdx.x*blockDim.x + threadIdx.x;
  if (e < E){
    int d = dstv[e];
    int p = atomicAdd(&cursor[d], 1);
    csr[p] = srcv[e];
  }
}

// ---------------------------------------------------------------------------
// BN stats + coef
// ---------------------------------------------------------------------------
__global__ __launch_bounds__(256)
void k_bn_stats(const unsigned short* __restrict__ x, float* __restrict__ psum,
                float* __restrict__ psq, int N, int HC){
  int f   = threadIdx.x & (HC-1);
  int sub = threadIdx.x / HC;
  int subs = 256 / HC;
  int slot = blockIdx.x*subs + sub;
  int stride = gridDim.x*subs;
  float s = 0.f, q = 0.f;
  for (int r = slot; r < N; r += stride){
    float v = bf2f(x[(size_t)r*HC + f]);
    s += v; q += v*v;
  }
  psum[(size_t)slot*HC + f] = s;
  psq [(size_t)slot*HC + f] = q;
}

__global__ __launch_bounds__(256)
void k_bn_coef(const float* __restrict__ psum, const float* __restrict__ psq,
               const float* __restrict__ g, const float* __restrict__ b,
               float* __restrict__ sc, float* __restrict__ sh,
               float invN, int HC, int nb){
  int f = blockIdx.x;
  int t = threadIdx.x;
  float s = 0.f, q = 0.f;
  for (int r = t; r < nb; r += 256){
    s += psum[(size_t)r*HC + f];
    q += psq [(size_t)r*HC + f];
  }
  #pragma unroll
  for (int d = 1; d < 64; d <<= 1){
    s += __shfl_xor(s, d, 64);
    q += __shfl_xor(q, d, 64);
  }
  __shared__ float ss[4], qq[4];
  int wv = t >> 6, ln = t & 63;
  if (ln == 0){ ss[wv] = s; qq[wv] = q; }
  __syncthreads();
  if (t == 0){
    s = ss[0]+ss[1]+ss[2]+ss[3];
    q = qq[0]+qq[1]+qq[2]+qq[3];
    float mu  = s*invN;
    float var = q*invN - mu*mu;
    float rs  = rsqrtf(var + 1e-5f) * g[f];
    sc[f] = rs;
    sh[f] = b[f] - mu*rs;
  }
}

// ---------------------------------------------------------------------------
// MFMA GEMM. BM=64, BN = full width.
// AFMT 0: A fp32, 3-term hi/lo. AFMT 1: A bf16 + BN affine + lrelu(0.1),
// rounded to bf16 -> 2-term. AFMT 2: A bf16 exact, 2-term.
// ---------------------------------------------------------------------------
template<int BN, int AFMT>
__global__ __launch_bounds__((BN==64)?256:512)
void gemm_mfma(const void* __restrict__ Av, const unsigned short* __restrict__ Bh,
               const unsigned short* __restrict__ Bl,
               const float* __restrict__ bnsc, const float* __restrict__ bnsh,
               const float* __restrict__ a_s, const float* __restrict__ a_d,
               unsigned short* __restrict__ Pb, float* __restrict__ Ds,
               float* __restrict__ Dd, int M, int K){
  constexpr int WAVES   = (BN==64) ? 4 : 8;
  constexpr int BLOCK   = WAVES*64;
  constexpr int WAVES_N = BN/64;
  constexpr int WAVES_M = WAVES/WAVES_N;
  constexpr int WM      = 64/WAVES_M;
  constexpr int MF      = WM/16;
  constexpr int CH      = (BN==512)?64 : (BN==256)?32 : 8;
  constexpr int TERMS   = (AFMT==0) ? 3 : 2;
  const int Kp = (K + 63) & ~(int)63;

  __shared__ char lds[(TERMS==3)?16384:8192];

  int tid  = threadIdx.x;
  int lane = tid & 63;
  int wid  = tid >> 6;
  int wn = wid % WAVES_N;
  int wm = wid / WAVES_N;
  int n0w = wn*64;
  int wm0 = wm*WM;
  int m0 = blockIdx.x * 64;

  f32x4 acc[MF][4];
  #pragma unroll
  for (int i = 0; i < MF; ++i)
    #pragma unroll
    for (int j = 0; j < 4; ++j)
      acc[i][j] = (f32x4){0.f,0.f,0.f,0.f};

  constexpr int SITER = 512/BLOCK;

  for (int k0 = 0; k0 < Kp; k0 += 64){
    __syncthreads();
    #pragma unroll
    for (int it = 0; it < SITER; ++it){
      int i = it*BLOCK + tid;
      int row = i >> 3, c8 = i & 7;
      int gm = m0 + row;
      int gk = k0 + c8*8;
      int off = row*128 + ((c8 ^ (row&7))<<4);
      if constexpr (AFMT == 2){
        short8 hv = {0,0,0,0,0,0,0,0};
        if (gm < M) hv = *(const short8*)((const unsigned short*)Av + (size_t)gm*K + gk);
        *(short8*)(lds + off) = hv;
      } else if constexpr (AFMT == 1){
        short8 raw = {0,0,0,0,0,0,0,0};
        if (gm < M) raw = *(const short8*)((const unsigned short*)Av + (size_t)gm*K + gk);
        short8 hi;
        #pragma unroll
        for (int j=0;j<8;++j){
          float u = bf2f((unsigned short)raw[j])*bnsc[gk+j] + bnsh[gk+j];
          u = u > 0.f ? u : 0.1f*u;
          if (gm >= M) u = 0.f;
          hi[j] = (short)f2bf(u);
        }
        *(short8*)(lds + off) = hi;
      } else {
        const float* A = (const float*)Av;
        float v[8];
        if (gm < M && gk + 8 <= K){
          const float* ap = A + (size_t)gm*K + gk;
          float4 x0 = *(const float4*)ap;
          float4 x1 = *(const float4*)(ap+4);
          v[0]=x0.x; v[1]=x0.y; v[2]=x0.z; v[3]=x0.w;
          v[4]=x1.x; v[5]=x1.y; v[6]=x1.z; v[7]=x1.w;
        } else {
          #pragma unroll
          for (int j=0;j<8;++j){
            int gkj = gk + j;
            v[j] = (gm < M && gkj < K) ? A[(size_t)gm*K + gkj] : 0.0f;
          }
        }
        short8 hi, lo;
        #pragma unroll
        for (int j=0;j<8;++j){
          unsigned short hb = f2bf(v[j]);
          hi[j] = (short)hb;
          lo[j] = (short)f2bf(v[j] - bf2f(hb));
        }
        *(short8*)(lds + off) = hi;
        *(short8*)(lds + 8192 + off) = lo;
      }
    }
    __syncthreads();
    #pragma unroll
    for (int kk = 0; kk < 2; ++kk){
      short8 bhf[4], blf[4];
      #pragma unroll
      for (int nf = 0; nf < 4; ++nf){
        int ncol = n0w + nf*16 + (lane & 15);
        int kidx = k0 + kk*32 + ((lane>>4)<<3);
        size_t bo = (size_t)ncol*Kp + kidx;
        bhf[nf] = *(const short8*)(Bh + bo);
        blf[nf] = *(const short8*)(Bl + bo);
      }
      #pragma unroll
      for (int mt = 0; mt < MF; ++mt){
        int row = wm0 + mt*16 + (lane & 15);
        int c8 = kk*4 + (lane>>4);
        int off = row*128 + ((c8 ^ (row&7))<<4);
        short8 ah = *(const short8*)(lds + off);
        #pragma unroll
        for (int nf = 0; nf < 4; ++nf){
          acc[mt][nf] = __builtin_amdgcn_mfma_f32_16x16x32_bf16(ah, bhf[nf], acc[mt][nf], 0,0,0);
          acc[mt][nf] = __builtin_amdgcn_mfma_f32_16x16x32_bf16(ah, blf[nf], acc[mt][nf], 0,0,0);
        }
        if constexpr (TERMS == 3){
          short8 al = *(const short8*)(lds + 8192 + off);
          #pragma unroll
          for (int nf = 0; nf < 4; ++nf)
            acc[mt][nf] = __builtin_amdgcn_mfma_f32_16x16x32_bf16(al, bhf[nf], acc[mt][nf], 0,0,0);
        }
      }
    }
  }

  float asv[4], adv[4];
  #pragma unroll
  for (int nf=0; nf<4; ++nf){
    int gcol = n0w + nf*16 + (lane&15);
    asv[nf] = a_s[gcol];
    adv[nf] = a_d[gcol];
  }
  #pragma unroll
  for (int mt = 0; mt < MF; ++mt){
    #pragma unroll
    for (int r = 0; r < 4; ++r){
      int gm = m0 + wm0 + mt*16 + ((lane>>4)<<2) + r;
      bool ok = gm < M;
      #pragma unroll
      for (int nf=0;nf<4;++nf){
        if (ok) Pb[(size_t)gm*BN + n0w + nf*16 + (lane&15)] = f2bf(acc[mt][nf][r]);
      }
      if constexpr (CH == 64){
        float ps = acc[mt][0][r]*asv[0] + acc[mt][1][r]*asv[1]
                 + acc[mt][2][r]*asv[2] + acc[mt][3][r]*asv[3];
        float pd = acc[mt][0][r]*adv[0] + acc[mt][1][r]*adv[1]
                 + acc[mt][2][r]*adv[2] + acc[mt][3][r]*adv[3];
        #pragma unroll
        for (int d2=1; d2<16; d2<<=1){ ps += __shfl_xor(ps,d2,64); pd += __shfl_xor(pd,d2,64); }
        if (ok && (lane&15)==0){
          int head = n0w >> 6;
          Ds[(size_t)gm*8 + head] = ps;
          Dd[(size_t)gm*8 + head] = pd;
        }
      } else if constexpr (CH == 32){
        float ps0 = acc[mt][0][r]*asv[0] + acc[mt][1][r]*asv[1];
        float ps1 = acc[mt][2][r]*asv[2] + acc[mt][3][r]*asv[3];
        float pd0 = acc[mt][0][r]*adv[0] + acc[mt][1][r]*adv[1];
        float pd1 = acc[mt][2][r]*adv[2] + acc[mt][3][r]*adv[3];
        #pragma unroll
        for (int d2=1; d2<16; d2<<=1){
          ps0 += __shfl_xor(ps0,d2,64); ps1 += __shfl_xor(ps1,d2,64);
          pd0 += __shfl_xor(pd0,d2,64); pd1 += __shfl_xor(pd1,d2,64);
        }
        if (ok && (lane&15)==0){
          int head = n0w >> 5;
          Ds[(size_t)gm*8 + head]     = ps0;
          Ds[(size_t)gm*8 + head + 1] = ps1;
          Dd[(size_t)gm*8 + head]     = pd0;
          Dd[(size_t)gm*8 + head + 1] = pd1;
        }
      } else {
        #pragma unroll
        for (int nf=0;nf<4;++nf){
          float ps = acc[mt][nf][r]*asv[nf];
          float pd = acc[mt][nf][r]*adv[nf];
          #pragma unroll
          for (int d2=1; d2<8; d2<<=1){ ps += __shfl_xor(ps,d2,64); pd += __shfl_xor(pd,d2,64); }
          if (ok && (lane&7)==0){
            int head = nf*2 + ((lane>>3)&1);
            Ds[(size_t)gm*8 + head] = ps;
            Dd[(size_t)gm*8 + head] = pd;
          }
        }
      }
    }
  }
}

// ---------------------------------------------------------------------------
// aggregation: bf16 h (Pb, stride HC) + fp32 dots Ds/Dd [N][8].
// Fast path (deg<64): lane-split edge parallelism — HC=64: 8 edges/iter
// (8 lanes x 8 feats), HC=256: 2 edges/iter, HC=512: 1 edge/iter.
// ---------------------------------------------------------------------------
template<int HC, int ACT>
__global__ __launch_bounds__(256)
void k_agg(const unsigned short* __restrict__ Pb, const float* __restrict__ Ds,
           const float* __restrict__ Dd, const int* __restrict__ off,
           const int* __restrict__ csr, const float* __restrict__ bias,
           unsigned short* __restrict__ outb, int N){
  __shared__ float salpha[4][512];
  int lane = threadIdx.x & 63;
  int wid  = threadIdx.x >> 6;
  int n = blockIdx.x*4 + wid;
  if (n >= N) return;
  int o0 = off[n], deg = off[n+1]-o0;

  float aldn[8];
  {
    const float* dn = Dd + (unsigned)n*8u;
    float4 x0 = *(const float4*)dn;
    float4 x1 = *(const float4*)(dn+4);
    aldn[0]=x0.x; aldn[1]=x0.y; aldn[2]=x0.z; aldn[3]=x0.w;
    aldn[4]=x1.x; aldn[5]=x1.y; aldn[6]=x1.z; aldn[7]=x1.w;
  }

  if (deg < 64){
    int nE = deg + 1;
    int myidx = (lane < deg) ? csr[o0+lane] : n;
    bool active = (lane < nE);
    float v[8];
    {
      const float* dp = Ds + (unsigned)myidx*8u;
      float4 x0 = *(const float4*)dp;
      float4 x1 = *(const float4*)(dp+4);
      float t[8] = {x0.x,x0.y,x0.z,x0.w,x1.x,x1.y,x1.z,x1.w};
      #pragma unroll
      for (int h=0;h<8;++h){
        float u = t[h] + aldn[h];
        u = u > 0.f ? u : 0.2f*u;
        v[h] = active ? u : -1e30f;
      }
    }
    float m[8];
    #pragma unroll
    for (int h=0;h<8;++h) m[h]=v[h];
    #pragma unroll
    for (int d=1; d<64; d<<=1)
      #pragma unroll
      for (int h=0;h<8;++h) m[h] = fmaxf(m[h], __shfl_xor(m[h], d, 64));
    float sv[8], s[8];
    #pragma unroll
    for (int h=0;h<8;++h){ sv[h] = active ? __expf(v[h]-m[h]) : 0.f; s[h]=sv[h]; }
    #pragma unroll
    for (int d=1; d<64; d<<=1)
      #pragma unroll
      for (int h=0;h<8;++h) s[h] += __shfl_xor(s[h], d, 64);
    if (active){
      #pragma unroll
      for (int h=0;h<8;++h) salpha[wid][lane*8+h] = sv[h] / (s[h] + 1e-16f);
    }
    asm volatile("s_waitcnt lgkmcnt(0)" ::: "memory");

    if constexpr (HC == 512){
      int myh = lane >> 3;
      float acc[8] = {0,0,0,0,0,0,0,0};
      const unsigned short* Pl = Pb + lane*8;
      for (int e=0; e<nE; ++e){
        int src = __shfl(myidx, e, 64);
        float alpha = salpha[wid][e*8 + myh];
        short8 w = *(const short8*)(Pl + (unsigned)src*512u);
        #pragma unroll
        for (int j=0;j<8;++j) acc[j] += alpha * bf2f((unsigned short)w[j]);
      }
      #pragma unroll
      for (int j=0;j<8;++j){
        int f = lane*8 + j;
        float u = acc[j] + bias[f];
        if (ACT == 1) u = fmaxf(u, 0.0f);
        outb[(unsigned)n*512u + f] = f2bf(u);
      }
    } else if constexpr (HC == 256){
      int sub = lane >> 5, fl = lane & 31;
      int h = fl >> 2;
      float acc[8] = {0,0,0,0,0,0,0,0};
      const unsigned short* Pl = Pb + fl*8;
      for (int e=0; e<nE; e+=2){
        int eg = e + sub;
        bool val = eg < nE;
        int src = __shfl(myidx, val ? eg : 0, 64);
        float alpha = val ? salpha[wid][eg*8 + h] : 0.f;
        short8 w = *(const short8*)(Pl + (unsigned)src*256u);
        #pragma unroll
        for (int j=0;j<8;++j) acc[j] += alpha * bf2f((unsigned short)w[j]);
      }
      #pragma unroll
      for (int j=0;j<8;++j) acc[j] += __shfl_xor(acc[j], 32, 64);
      if (sub == 0){
        short8 ov;
        #pragma unroll
        for (int j=0;j<8;++j){
          int f = fl*8 + j;
          float u = acc[j] + bias[f];
          if (ACT == 1) u = fmaxf(u, 0.0f);
          ov[j] = (short)f2bf(u);
        }
        *(short8*)(outb + (unsigned)n*256u + fl*8) = ov;
      }
    } else { // HC == 64: 8 edges in flight, 8 lanes x 8 feats (1 head/lane)
      int sub = lane >> 3, fl = lane & 7;
      float acc[8] = {0,0,0,0,0,0,0,0};
      const unsigned short* Pl = Pb + fl*8;
      for (int e=0; e<nE; e+=8){
        int eg = e + sub;
        bool val = eg < nE;
        int src = __shfl(myidx, val ? eg : 0, 64);
        float alpha = val ? salpha[wid][eg*8 + fl] : 0.f;
        short8 w = *(const short8*)(Pl + (unsigned)src*64u);
        #pragma unroll
        for (int j=0;j<8;++j) acc[j] += alpha * bf2f((unsigned short)w[j]);
      }
      #pragma unroll
      for (int j=0;j<8;++j){
        acc[j] += __shfl_xor(acc[j], 8, 64);
        acc[j] += __shfl_xor(acc[j], 16, 64);
        acc[j] += __shfl_xor(acc[j], 32, 64);
      }
      if (sub == 0){
        short8 ov;
        #pragma unroll
        for (int j=0;j<8;++j){
          int f = fl*8 + j;
          float u = acc[j] + bias[f];
          if (ACT == 1) u = fmaxf(u, 0.0f);
          ov[j] = (short)f2bf(u);
        }
        *(short8*)(outb + (unsigned)n*64u + fl*8) = ov;
      }
    }
  } else {
    constexpr int R = HC/64;
    int myh = lane >> 3;
    float m[8];
    #pragma unroll
    for (int h=0;h<8;++h) m[h] = -1e30f;
    for (int e = lane; e <= deg; e += 64){
      int src = (e < deg) ? csr[o0+e] : n;
      const float* ap = Ds + (size_t)src*8;
      #pragma unroll
      for (int h=0;h<8;++h){
        float u = ap[h] + aldn[h];
        u = u > 0.f ? u : 0.2f*u;
        m[h] = fmaxf(m[h], u);
      }
    }
    #pragma unroll
    for (int d=1; d<64; d<<=1)
      #pragma unroll
      for (int h=0;h<8;++h) m[h] = fmaxf(m[h], __shfl_xor(m[h], d, 64));
    float s[8] = {0,0,0,0,0,0,0,0};
    for (int e = lane; e <= deg; e += 64){
      int src = (e < deg) ? csr[o0+e] : n;
      const float* ap = Ds + (size_t)src*8;
      #pragma unroll
      for (int h=0;h<8;++h){
        float u = ap[h] + aldn[h];
        u = u > 0.f ? u : 0.2f*u;
        s[h] += __expf(u - m[h]);
      }
    }
    #pragma unroll
    for (int d=1; d<64; d<<=1)
      #pragma unroll
      for (int h=0;h<8;++h) s[h] += __shfl_xor(s[h], d, 64);
    float mh = m[myh];
    float rsh = 1.0f/(s[myh] + 1e-16f);
    float adh = aldn[myh];
    float acc[R];
    #pragma unroll
    for (int j=0;j<R;++j) acc[j]=0.f;
    for (int e = 0; e <= deg; ++e){
      int src = (e < deg) ? csr[o0+e] : n;
      float u = Ds[(size_t)src*8 + myh] + adh;
      u = u > 0.f ? u : 0.2f*u;
      float alpha = __expf(u - mh) * rsh;
      const unsigned short* hp = Pb + (size_t)src*HC + lane*R;
      if constexpr (R == 1){
        acc[0] += alpha * bf2f(hp[0]);
      } else if constexpr (R == 4){
        short4v w = *(const short4v*)hp;
        #pragma unroll
        for (int j=0;j<4;++j) acc[j] += alpha * bf2f((unsigned short)w[j]);
      } else {
        short8 w = *(const short8*)hp;
        #pragma unroll
        for (int j=0;j<8;++j) acc[j] += alpha * bf2f((unsigned short)w[j]);
      }
    }
    #pragma unroll
    for (int j = 0; j < R; ++j){
      int f = lane*R + j;
      float u = acc[j] + bias[f];
      if (ACT == 1) u = fmaxf(u, 0.0f);
      outb[(size_t)n*HC + f] = f2bf(u);
    }
  }
}

// ---------------------------------------------------------------------------
// conv32 GEMM: bf16 A [M,512] x fp32 W [512,8] -> fp32 h8 [M,8]
// ---------------------------------------------------------------------------
__global__ __launch_bounds__(256)
void gemm8(const unsigned short* __restrict__ Qb, const float* __restrict__ W,
           float* __restrict__ h8, int M){
  int lane = threadIdx.x & 63;
  int gw = (blockIdx.x*blockDim.x + threadIdx.x) >> 6;
  int nw = (gridDim.x*blockDim.x) >> 6;
  float w[8][8];
  const float* wp = W + lane*64;
  #pragma unroll
  for (int j=0;j<8;++j){
    float4 a = *(const float4*)(wp + j*8);
    float4 b = *(const float4*)(wp + j*8 + 4);
    w[j][0]=a.x; w[j][1]=a.y; w[j][2]=a.z; w[j][3]=a.w;
    w[j][4]=b.x; w[j][5]=b.y; w[j][6]=b.z; w[j][7]=b.w;
  }
  for (int n = gw; n < M; n += nw){
    short8 v8 = *(const short8*)(Qb + (size_t)n*512 + lane*8);
    float p[8] = {0,0,0,0,0,0,0,0};
    #pragma unroll
    for (int j=0;j<8;++j){
      float x = bf2f((unsigned short)v8[j]);
      #pragma unroll
      for (int o=0;o<8;++o) p[o] += x * w[j][o];
    }
    #pragma unroll
    for (int d=1; d<64; d<<=1)
      #pragma unroll
      for (int o=0;o<8;++o) p[o] += __shfl_xor(p[o], d, 64);
    if (lane == 0){
      float4 y0 = make_float4(p[0],p[1],p[2],p[3]);
      float4 y1 = make_float4(p[4],p[5],p[6],p[7]);
      *(float4*)(h8 + (size_t)n*8)     = y0;
      *(float4*)(h8 + (size_t)n*8 + 4) = y1;
    }
  }
}

// ---------------------------------------------------------------------------
// final conv: wave-per-node
// ---------------------------------------------------------------------------
__global__ __launch_bounds__(256)
void k_final(const float* __restrict__ h8, const float* __restrict__ a_s,
             const float* __restrict__ a_d, const int* __restrict__ off,
             const int* __restrict__ csr, const float* __restrict__ b32,
             float* __restrict__ outp, int N){
  int lane = threadIdx.x & 63;
  int wv   = threadIdx.x >> 6;
  int n = blockIdx.x*4 + wv;
  if (n >= N) return;
  int o0 = off[n], deg = off[n+1]-o0;
  float asv[8], adv[8];
  #pragma unroll
  for (int h=0;h<8;++h){ asv[h]=a_s[h]; adv[h]=a_d[h]; }
  float aldn[8];
  {
    const float* hp = h8 + (size_t)n*8;
    float4 x0 = *(const float4*)hp;
    float4 x1 = *(const float4*)(hp+4);
    float hn[8] = {x0.x,x0.y,x0.z,x0.w,x1.x,x1.y,x1.z,x1.w};
    #pragma unroll
    for (int h=0;h<8;++h) aldn[h] = hn[h]*adv[h];
  }

  if (deg < 64){
    int nE = deg + 1;
    int src = (lane < deg) ? csr[o0+lane] : n;
    bool act = (lane < nE);
    float hs[8];
    {
      const float* hp = h8 + (size_t)src*8;
      float4 x0 = *(const float4*)hp;
      float4 x1 = *(const float4*)(hp+4);
      hs[0]=x0.x; hs[1]=x0.y; hs[2]=x0.z; hs[3]=x0.w;
      hs[4]=x1.x; hs[5]=x1.y; hs[6]=x1.z; hs[7]=x1.w;
    }
    float v[8];
    #pragma unroll
    for (int h=0;h<8;++h){
      float u = hs[h]*asv[h] + aldn[h];
      u = u > 0.f ? u : 0.2f*u;
      v[h] = act ? u : -1e30f;
    }
    float m[8];
    #pragma unroll
    for (int h=0;h<8;++h) m[h]=v[h];
    #pragma unroll
    for (int d=1; d<64; d<<=1)
      #pragma unroll
      for (int h=0;h<8;++h) m[h] = fmaxf(m[h], __shfl_xor(m[h], d, 64));
    float s[8], t[8];
    #pragma unroll
    for (int h=0;h<8;++h){
      float e = act ? __expf(v[h]-m[h]) : 0.f;
      s[h]=e; t[h]=e*hs[h];
    }
    #pragma unroll
    for (int d=1; d<64; d<<=1)
      #pragma unroll
      for (int h=0;h<8;++h){
        s[h] += __shfl_xor(s[h], d, 64);
        t[h] += __shfl_xor(t[h], d, 64);
      }
    if (lane == 0){
      float o = 0.f;
      #pragma unroll
      for (int h=0;h<8;++h) o += t[h]/(s[h]+1e-16f);
      o = o*0.125f + b32[0];
      outp[n] = 1.0f/(1.0f + __expf(-o));
    }
  } else if (lane == 0){
    float m[8], s[8], agg[8];
    #pragma unroll
    for (int h=0;h<8;++h){ m[h]=-1e30f; s[h]=0.f; agg[h]=0.f; }
    for (int e = 0; e <= deg; ++e){
      int src = (e < deg) ? csr[o0+e] : n;
      #pragma unroll
      for (int h=0;h<8;++h){
        float u = h8[(size_t)src*8+h]*asv[h] + aldn[h];
        u = u > 0.f ? u : 0.2f*u;
        m[h] = fmaxf(m[h], u);
      }
    }
    for (int e = 0; e <= deg; ++e){
      int src = (e < deg) ? csr[o0+e] : n;
      #pragma unroll
      for (int h=0;h<8;++h){
        float u = h8[(size_t)src*8+h]*asv[h] + aldn[h];
        u = u > 0.f ? u : 0.2f*u;
        float ex = __expf(u - m[h]);
        s[h] += ex;
        agg[h] += ex * h8[(size_t)src*8+h];
      }
    }
    float o = 0.f;
    #pragma unroll
    for (int h=0;h<8;++h) o += agg[h]/(s[h]+1e-16f);
    o = o*0.125f + b32[0];
    outp[n] = 1.0f/(1.0f + __expf(-o));
  }
}

// ---------------------------------------------------------------------------
extern "C" void kernel_launch(void* const* d_in, const int* in_sizes, int n_in,
                              void* d_out, int out_size, void* d_ws, size_t ws_size,
                              hipStream_t stream){
  int N = in_sizes[0]/3;
  int E = in_sizes[1]/2;
  const float* x    = (const float*)d_in[0];
  const int*   ei   = (const int*)  d_in[1];
  const float* W11  = (const float*)d_in[2];
  const float* as11 = (const float*)d_in[3];
  const float* ad11 = (const float*)d_in[4];
  const float* b11  = (const float*)d_in[5];
  const float* W12  = (const float*)d_in[6];
  const float* as12 = (const float*)d_in[7];
  const float* ad12 = (const float*)d_in[8];
  const float* b12  = (const float*)d_in[9];
  const float* g1   = (const float*)d_in[10];
  const float* be1  = (const float*)d_in[11];
  const float* W21  = (const float*)d_in[12];
  const float* as21 = (const float*)d_in[13];
  const float* ad21 = (const float*)d_in[14];
  const float* b21  = (const float*)d_in[15];
  const float* W22  = (const float*)d_in[16];
  const float* as22 = (const float*)d_in[17];
  const float* ad22 = (const float*)d_in[18];
  const float* b22  = (const float*)d_in[19];
  const float* g2   = (const float*)d_in[20];
  const float* be2  = (const float*)d_in[21];
  const float* W31  = (const float*)d_in[22];
  const float* as31 = (const float*)d_in[23];
  const float* ad31 = (const float*)d_in[24];
  const float* b31  = (const float*)d_in[25];
  const float* W32  = (const float*)d_in[26];
  const float* as32 = (const float*)d_in[27];
  const float* ad32 = (const float*)d_in[28];
  const float* b32  = (const float*)d_in[29];

  char* ws = (char*)d_ws;
  size_t o = 0;
  auto alloc = [&](size_t bytes)->char*{
    char* p = ws + o;
    o = (o + bytes + 255) & ~(size_t)255;
    return p;
  };
  int*   deg    = (int*)  alloc((size_t)N*4);
  int*   off    = (int*)  alloc((size_t)(N+1)*4);
  int*   cursor = (int*)  alloc((size_t)N*4);
  int*   csr    = (int*)  alloc((size_t)E*4);
  int*   bsum   = (int*)  alloc(64*4);
  int*   bpre   = (int*)  alloc(64*4);
  unsigned short* bh = (unsigned short*)alloc(221184*2);
  unsigned short* bl = (unsigned short*)alloc(221184*2);
  float* h8     = (float*)alloc((size_t)N*8*4);
  float* psum   = (float*)alloc(1024*64*4);
  float* psq    = (float*)alloc(1024*64*4);
  float* bnsc   = (float*)alloc(1024);
  float* bnsh   = (float*)alloc(1024);
  unsigned short* Pb = (unsigned short*)alloc((size_t)N*512*2);
  unsigned short* Qb = (unsigned short*)alloc((size_t)N*512*2);
  float* Dsb    = (float*)alloc((size_t)N*8*4);
  float* Ddb    = (float*)alloc((size_t)N*8*4);
  (void)ws_size;

  const int BT11=0, BT12=4096, BT21=8192, BT22=24576, BT31=90112;

  // ---- CSR build + weight prep ----
  hipMemsetAsync(deg, 0, (size_t)N*4, stream);
  int eb = (E+255)/256;
  int nb1k = (N+1023)/1024;
  k_deg_prep<<<eb, 256, 0, stream>>>(ei+E, deg, E, W11, W12, W21, W22, W31, bh, bl);
  k_scan1<<<nb1k, 1024, 0, stream>>>(deg, off, bsum, N);
  k_scan2<<<1, 64, 0, stream>>>(bsum, bpre, nb1k);
  k_scan3<<<nb1k, 1024, 0, stream>>>(deg, off, bpre, cursor, N);
  k_fill<<<eb, 256, 0, stream>>>(ei, ei+E, cursor, csr, E);

  int mb = (N+63)/64;
  int nb4 = (N+3)/4;
  float invN = 1.0f/(float)N;

  // ---- conv11: 3 -> 64 (A fp32, 3-term), relu ----
  gemm_mfma<64,0><<<mb, 256, 0, stream>>>(x, bh+BT11, bl+BT11, nullptr, nullptr,
                                          as11, ad11, Pb, Dsb, Ddb, N, 3);
  k_agg<64,1><<<nb4, 256, 0, stream>>>(Pb, Dsb, Ddb, off, csr, b11, Qb, N);

  // ---- conv12: 64 -> 64 (A bf16 exact, 2-term), BN stats after ----
  gemm_mfma<64,2><<<mb, 256, 0, stream>>>(Qb, bh+BT12, bl+BT12, nullptr, nullptr,
                                          as12, ad12, Pb, Dsb, Ddb, N, 64);
  k_agg<64,0><<<nb4, 256, 0, stream>>>(Pb, Dsb, Ddb, off, csr, b12, Qb, N);
  k_bn_stats<<<256, 256, 0, stream>>>(Qb, psum, psq, N, 64);
  k_bn_coef<<<64, 256, 0, stream>>>(psum, psq, g1, be1, bnsc, bnsh, invN, 64, 1024);

  // ---- conv21: 64 -> 256 (BN+lrelu fused -> bf16, 2-term), relu out ----
  gemm_mfma<256,1><<<mb, 512, 0, stream>>>(Qb, bh+BT21, bl+BT21, bnsc, bnsh,
                                           as21, ad21, Pb, Dsb, Ddb, N, 64);
  k_agg<256,1><<<nb4, 256, 0, stream>>>(Pb, Dsb, Ddb, off, csr, b21, Qb, N);

  // ---- conv22: 256 -> 256 (A bf16 exact, 2-term), BN stats ----
  gemm_mfma<256,2><<<mb, 512, 0, stream>>>(Qb, bh+BT22, bl+BT22, nullptr, nullptr,
                                           as22, ad22, Pb, Dsb, Ddb, N, 256);
  k_agg<256,0><<<nb4, 256, 0, stream>>>(Pb, Dsb, Ddb, off, csr, b22, Qb, N);
  k_bn_stats<<<256, 256, 0, stream>>>(Qb, psum, psq, N, 256);
  k_bn_coef<<<256, 256, 0, stream>>>(psum, psq, g2, be2, bnsc, bnsh, invN, 256, 256);

  // ---- conv31: 256 -> 512 (BN+lrelu fused -> bf16, 2-term), relu out ----
  gemm_mfma<512,1><<<mb, 512, 0, stream>>>(Qb, bh+BT31, bl+BT31, bnsc, bnsh,
                                           as31, ad31, Pb, Dsb, Ddb, N, 256);
  k_agg<512,1><<<nb4, 256, 0, stream>>>(Pb, Dsb, Ddb, off, csr, b31, Qb, N);

  // ---- conv32: 512 -> 8x1, concat=False, mean, sigmoid ----
  gemm8<<<1024, 256, 0, stream>>>(Qb, W32, h8, N);
  k_final<<<nb4, 256, 0, stream>>>(h8, as32, ad32, off, csr, b32,
                                   (float*)d_out, N);
}